// Round 1
// baseline (330.190 us; speedup 1.0000x reference)
//
#include <hip/hip_runtime.h>

// Problem constants
#define HH 80
#define WW 80
#define NPIX 6400          // 80*80
#define NB 4               // batch
#define BN 25600           // NB * NPIX
#define CDIM 256
#define SCALE 0.17677669529663689f   // 32^-0.5

// ---------------------------------------------------------------------------
// Kernel 1: qkv[o][n] = sum_c w_qkv[o][c] * Y[c][n]
//   Y[c][n]: c<128 -> rgb[b,c,:,:], else ir[b,c-128,:,:];  n = b*NPIX + pix
//   Tile 64(o) x 64(n), K-chunks of 16, 256 threads, 4x4 microtile.
// ---------------------------------------------------------------------------
__global__ __launch_bounds__(256) void gemm_qkv_k(
    const float* __restrict__ rgb, const float* __restrict__ ir,
    const float* __restrict__ w, float* __restrict__ qkv)
{
    __shared__ float As[16][65];   // [c][o], pad 65 to break stride-64 write conflicts
    __shared__ float Bs[16][64];   // [c][n]
    const int tid = threadIdx.x;
    const int tx = tid & 15, ty = tid >> 4;
    const int n0 = blockIdx.x * 64;
    const int o0 = blockIdx.y * 64;
    const int b  = n0 / NPIX;       // 6400 % 64 == 0 -> tile never straddles b
    const int pix0 = n0 - b * NPIX;
    const float* ybase_rgb = rgb + (size_t)b * 128 * NPIX;
    const float* ybase_ir  = ir  + (size_t)b * 128 * NPIX;

    const int cW = tid & 15;   // c within chunk (W load)
    const int oW = tid >> 4;   // o fragment    (W load)
    const int nl = tid & 63;   // n within tile (Y load)
    const int cl = tid >> 6;   // c group       (Y load)

    float acc[4][4] = {};

    for (int c0 = 0; c0 < CDIM; c0 += 16) {
        #pragma unroll
        for (int k = 0; k < 4; ++k)
            As[cW][oW + k * 16] = w[(size_t)(o0 + oW + k * 16) * CDIM + c0 + cW];
        #pragma unroll
        for (int p = 0; p < 4; ++p) {
            int c = c0 + cl + p * 4;
            const float* src = (c < 128) ? (ybase_rgb + (size_t)c * NPIX)
                                         : (ybase_ir + (size_t)(c - 128) * NPIX);
            Bs[cl + p * 4][nl] = src[pix0 + nl];
        }
        __syncthreads();
        #pragma unroll
        for (int kk = 0; kk < 16; ++kk) {
            float a[4], bv[4];
            #pragma unroll
            for (int i = 0; i < 4; ++i) a[i] = As[kk][ty * 4 + i];
            #pragma unroll
            for (int j = 0; j < 4; ++j) bv[j] = Bs[kk][tx * 4 + j];
            #pragma unroll
            for (int i = 0; i < 4; ++i)
                #pragma unroll
                for (int j = 0; j < 4; ++j)
                    acc[i][j] += a[i] * bv[j];
        }
        __syncthreads();
    }
    #pragma unroll
    for (int i = 0; i < 4; ++i) {
        int o = o0 + ty * 4 + i;
        #pragma unroll
        for (int j = 0; j < 4; ++j)
            qkv[(size_t)o * BN + n0 + tx * 4 + j] = acc[i][j];
    }
}

// ---------------------------------------------------------------------------
// Kernel 2: dilated local attention.
//   One thread per (b, dil, head, pixel). qkv layout [o][b*NPIX+pix] makes all
//   loads lane-coalesced. Unfold zero-padding: OOB neighbor -> score 0 (still
//   in softmax denominator), value 0.
//   Output X[c][n], c = dil*128 + head*32 + hd  (concat order of reference).
// ---------------------------------------------------------------------------
__global__ __launch_bounds__(256) void attn_k(
    const float* __restrict__ qkv, float* __restrict__ X)
{
    const int tid = threadIdx.x;
    const int pix = blockIdx.x * 256 + tid;
    const int b = blockIdx.z;
    const int dh = blockIdx.y;          // dil*4 + head
    const int dil_i = dh >> 2;
    const int head  = dh & 3;
    const int d = (dil_i == 0) ? 2 : 3;
    const int hh = pix / WW, ww = pix % WW;

    const int obase = dil_i * 128 + head * 32;
    const float* qp = qkv + (size_t)obase * BN + b * NPIX + pix;
    const float* kb = qkv + (size_t)(256 + obase) * BN + b * NPIX;
    const float* vb = qkv + (size_t)(512 + obase) * BN + b * NPIX;

    float q[32];
    #pragma unroll
    for (int hd = 0; hd < 32; ++hd) q[hd] = qp[(size_t)hd * BN];

    float sc[9];
    #pragma unroll
    for (int t = 0; t < 9; ++t) {
        int yy = hh + (t / 3 - 1) * d;
        int xx = ww + (t % 3 - 1) * d;
        float s = 0.f;
        if (yy >= 0 && yy < HH && xx >= 0 && xx < WW) {
            const float* kp = kb + yy * WW + xx;
            #pragma unroll
            for (int hd = 0; hd < 32; ++hd) s += q[hd] * kp[(size_t)hd * BN];
        }
        sc[t] = s * SCALE;              // OOB stays exactly 0
    }
    float m = sc[0];
    #pragma unroll
    for (int t = 1; t < 9; ++t) m = fmaxf(m, sc[t]);
    float sum = 0.f;
    #pragma unroll
    for (int t = 0; t < 9; ++t) { sc[t] = __expf(sc[t] - m); sum += sc[t]; }
    const float inv = 1.f / sum;

    float o[32];
    #pragma unroll
    for (int hd = 0; hd < 32; ++hd) o[hd] = 0.f;
    #pragma unroll
    for (int t = 0; t < 9; ++t) {
        int yy = hh + (t / 3 - 1) * d;
        int xx = ww + (t % 3 - 1) * d;
        if (yy >= 0 && yy < HH && xx >= 0 && xx < WW) {
            const float* vp = vb + yy * WW + xx;
            float wgt = sc[t] * inv;
            #pragma unroll
            for (int hd = 0; hd < 32; ++hd) o[hd] += wgt * vp[(size_t)hd * BN];
        }
    }
    float* xp = X + (size_t)obase * BN + b * NPIX + pix;
    #pragma unroll
    for (int hd = 0; hd < 32; ++hd) xp[(size_t)hd * BN] = o[hd];
}

// ---------------------------------------------------------------------------
// Kernel 3: out[n][co] = bias[co] + sum_c w_proj[co][c] * X[c][n] + Y[co][n]
//   (residual = y in BHWC). Same tile structure as kernel 1.
// ---------------------------------------------------------------------------
__global__ __launch_bounds__(256) void proj_k(
    const float* __restrict__ X, const float* __restrict__ wp,
    const float* __restrict__ bp,
    const float* __restrict__ rgb, const float* __restrict__ ir,
    float* __restrict__ out)
{
    __shared__ float As[16][65];
    __shared__ float Bs[16][64];
    const int tid = threadIdx.x;
    const int tx = tid & 15, ty = tid >> 4;
    const int n0 = blockIdx.x * 64;
    const int o0 = blockIdx.y * 64;
    const int b  = n0 / NPIX;
    const int pix0 = n0 - b * NPIX;

    const int cW = tid & 15;
    const int oW = tid >> 4;
    const int nl = tid & 63;
    const int cl = tid >> 6;

    float acc[4][4] = {};

    for (int c0 = 0; c0 < CDIM; c0 += 16) {
        #pragma unroll
        for (int k = 0; k < 4; ++k)
            As[cW][oW + k * 16] = wp[(size_t)(o0 + oW + k * 16) * CDIM + c0 + cW];
        #pragma unroll
        for (int p = 0; p < 4; ++p) {
            int c = c0 + cl + p * 4;
            Bs[cl + p * 4][nl] = X[(size_t)c * BN + n0 + nl];
        }
        __syncthreads();
        #pragma unroll
        for (int kk = 0; kk < 16; ++kk) {
            float a[4], bv[4];
            #pragma unroll
            for (int i = 0; i < 4; ++i) a[i] = As[kk][ty * 4 + i];
            #pragma unroll
            for (int j = 0; j < 4; ++j) bv[j] = Bs[kk][tx * 4 + j];
            #pragma unroll
            for (int i = 0; i < 4; ++i)
                #pragma unroll
                for (int j = 0; j < 4; ++j)
                    acc[i][j] += a[i] * bv[j];
        }
        __syncthreads();
    }

    const float* ybase_rgb = rgb + (size_t)b * 128 * NPIX;
    const float* ybase_ir  = ir  + (size_t)b * 128 * NPIX;
    #pragma unroll
    for (int i = 0; i < 4; ++i) {
        int co = o0 + ty * 4 + i;
        float bias = bp[co];
        const float* res = (co < 128) ? (ybase_rgb + (size_t)co * NPIX)
                                      : (ybase_ir + (size_t)(co - 128) * NPIX);
        #pragma unroll
        for (int j = 0; j < 4; ++j) {
            int n = n0 + tx * 4 + j;
            int pix = pix0 + tx * 4 + j;
            out[(size_t)n * CDIM + co] = acc[i][j] + bias + res[pix];
        }
    }
}

extern "C" void kernel_launch(void* const* d_in, const int* in_sizes, int n_in,
                              void* d_out, int out_size, void* d_ws, size_t ws_size,
                              hipStream_t stream) {
    const float* rgb    = (const float*)d_in[0];
    const float* ir     = (const float*)d_in[1];
    const float* w_qkv  = (const float*)d_in[2];
    const float* w_proj = (const float*)d_in[3];
    const float* b_proj = (const float*)d_in[4];
    float* out = (float*)d_out;

    float* qkv = (float*)d_ws;                 // 768 * 25600 floats = 78.6 MB
    float* X   = qkv + (size_t)768 * BN;       // 256 * 25600 floats = 26.2 MB

    gemm_qkv_k<<<dim3(BN / 64, 768 / 64), 256, 0, stream>>>(rgb, ir, w_qkv, qkv);
    attn_k<<<dim3(NPIX / 256, 8, NB), 256, 0, stream>>>(qkv, X);
    proj_k<<<dim3(BN / 64, CDIM / 64), 256, 0, stream>>>(X, w_proj, b_proj, rgb, ir, out);
}

// Round 2
// 178.046 us; speedup vs baseline: 1.8545x; 1.8545x over previous
//
#include <hip/hip_runtime.h>

#define HH 80
#define WW 80
#define NPIX 6400          // 80*80
#define NB 4
#define BN 25600           // NB * NPIX
#define CDIM 256
#define QKVC 768
#define SCALE 0.17677669529663689f   // 32^-0.5

typedef __attribute__((ext_vector_type(8))) short short8;
typedef __attribute__((ext_vector_type(4))) float floatx4;

__device__ __forceinline__ float b2f(ushort u) {
    return __uint_as_float(((uint)u) << 16);
}
__device__ __forceinline__ ushort f2b(float f) {
    uint u = __float_as_uint(f);
    return (ushort)((u + 0x7fffu + ((u >> 16) & 1u)) >> 16);   // RNE
}
__device__ __forceinline__ void unpack8(uint4 v, float* f) {
    f[0] = __uint_as_float(v.x << 16); f[1] = __uint_as_float(v.x & 0xffff0000u);
    f[2] = __uint_as_float(v.y << 16); f[3] = __uint_as_float(v.y & 0xffff0000u);
    f[4] = __uint_as_float(v.z << 16); f[5] = __uint_as_float(v.z & 0xffff0000u);
    f[6] = __uint_as_float(v.w << 16); f[7] = __uint_as_float(v.w & 0xffff0000u);
}

// ---------------------------------------------------------------------------
// Cast both weight matrices to bf16 (layout unchanged: [o][c], c contiguous).
// ---------------------------------------------------------------------------
__global__ __launch_bounds__(256) void cast_w_k(
    const float* __restrict__ wq, const float* __restrict__ wp,
    ushort* __restrict__ wqb, ushort* __restrict__ wpb)
{
    int i = blockIdx.x * 256 + threadIdx.x;
    if (i < QKVC * CDIM) wqb[i] = f2b(wq[i]);
    if (i < CDIM * CDIM) wpb[i] = f2b(wp[i]);
}

// ---------------------------------------------------------------------------
// Yb[n][c] = bf16(concat(rgb, ir))  — transpose BCHW -> [n][c] via LDS tile.
// Tile: 64 pixels x 32 channels. grid = (NPIX/64, CDIM/32, NB)
// ---------------------------------------------------------------------------
__global__ __launch_bounds__(256) void cast_y_k(
    const float* __restrict__ rgb, const float* __restrict__ ir,
    ushort* __restrict__ Yb)
{
    __shared__ ushort T[32][72];
    const int tid = threadIdx.x;
    const int pix0 = blockIdx.x * 64;
    const int cb = blockIdx.y;
    const int b = blockIdx.z;

    const int pl = tid & 63, cg = tid >> 6;
    #pragma unroll
    for (int cc = 0; cc < 32; cc += 4) {
        int c = cb * 32 + cc + cg;
        const float* src = (c < 128) ? (rgb + ((size_t)b * 128 + c) * NPIX)
                                     : (ir + ((size_t)b * 128 + (c - 128)) * NPIX);
        T[cc + cg][pl] = f2b(src[pix0 + pl]);
    }
    __syncthreads();
    const int nl = tid >> 2, c0 = (tid & 3) * 8;
    ushort tmp[8];
    #pragma unroll
    for (int j = 0; j < 8; ++j) tmp[j] = T[c0 + j][nl];
    uint4 v;
    v.x = tmp[0] | ((uint)tmp[1] << 16);
    v.y = tmp[2] | ((uint)tmp[3] << 16);
    v.z = tmp[4] | ((uint)tmp[5] << 16);
    v.w = tmp[6] | ((uint)tmp[7] << 16);
    *(uint4*)(&Yb[((size_t)(b * NPIX + pix0 + nl)) * CDIM + cb * 32 + c0]) = v;
}

// ---------------------------------------------------------------------------
// MFMA NT GEMM: qkvb[n][o] = sum_c Yb[n][c] * Wqb[o][c], bf16 in/out, f32 acc.
// 128x128 block tile, 4 waves each 64x64 (4x4 of 16x16x32 MFMA), BK=32.
// ---------------------------------------------------------------------------
__global__ __launch_bounds__(256) void gemm_qkv_mfma(
    const ushort* __restrict__ Yb, const ushort* __restrict__ Wb,
    ushort* __restrict__ qkvb)
{
    __shared__ __align__(16) ushort As[128 * 40];   // [n][k], +8 pad
    __shared__ __align__(16) ushort Bs[128 * 40];   // [o][k], +8 pad
    const int tid = threadIdx.x;
    const int lane = tid & 63;
    const int wave = tid >> 6;
    const int wr = wave >> 1, wc = wave & 1;
    const int l15 = lane & 15, quad = lane >> 4;
    const int n0 = blockIdx.x * 128;
    const int o0 = blockIdx.y * 128;

    const int sm = tid >> 2;           // staging row 0..63 (+64 second pass)
    const int sk = (tid & 3) * 8;      // staging k offset

    floatx4 acc[4][4] = {};

    for (int k0 = 0; k0 < CDIM; k0 += 32) {
        #pragma unroll
        for (int p = 0; p < 2; ++p) {
            int m = sm + p * 64;
            *(uint4*)(&As[m * 40 + sk]) =
                *(const uint4*)(&Yb[(size_t)(n0 + m) * CDIM + k0 + sk]);
            *(uint4*)(&Bs[m * 40 + sk]) =
                *(const uint4*)(&Wb[(size_t)(o0 + m) * CDIM + k0 + sk]);
        }
        __syncthreads();
        short8 af[4], bfr[4];
        #pragma unroll
        for (int i = 0; i < 4; ++i)
            af[i] = *(const short8*)(&As[(wr * 64 + i * 16 + l15) * 40 + quad * 8]);
        #pragma unroll
        for (int j = 0; j < 4; ++j)
            bfr[j] = *(const short8*)(&Bs[(wc * 64 + j * 16 + l15) * 40 + quad * 8]);
        #pragma unroll
        for (int i = 0; i < 4; ++i)
            #pragma unroll
            for (int j = 0; j < 4; ++j)
                acc[i][j] = __builtin_amdgcn_mfma_f32_16x16x32_bf16(
                    af[i], bfr[j], acc[i][j], 0, 0, 0);
        __syncthreads();
    }
    #pragma unroll
    for (int i = 0; i < 4; ++i)
        #pragma unroll
        for (int j = 0; j < 4; ++j)
            #pragma unroll
            for (int r = 0; r < 4; ++r) {
                int n = n0 + wr * 64 + i * 16 + quad * 4 + r;
                int o = o0 + wc * 64 + j * 16 + l15;
                qkvb[(size_t)n * QKVC + o] = f2b(acc[i][j][r]);
            }
}

// ---------------------------------------------------------------------------
// Dilated local attention, bf16 I/O, fp32 math.
// qkvb[n][o]: o in [0,256)=q, [256,512)=k, [512,768)=v.
// Xb[n][c], c = dil*128 + head*32 + hd (reference concat order).
// ---------------------------------------------------------------------------
__global__ __launch_bounds__(256) void attn_k(
    const ushort* __restrict__ qkvb, ushort* __restrict__ Xb)
{
    const int tid = threadIdx.x;
    const int pix = blockIdx.x * 256 + tid;
    const int b = blockIdx.z;
    const int dh = blockIdx.y;
    const int dil_i = dh >> 2, head = dh & 3;
    const int d = (dil_i == 0) ? 2 : 3;
    const int hh = pix / WW, ww = pix % WW;
    const int n = b * NPIX + pix;
    const int obase = dil_i * 128 + head * 32;

    float q[32];
    {
        const uint4* qp = (const uint4*)(qkvb + (size_t)n * QKVC + obase);
        #pragma unroll
        for (int m4 = 0; m4 < 4; ++m4) unpack8(qp[m4], q + 8 * m4);
    }

    float sc[9];
    #pragma unroll
    for (int t = 0; t < 9; ++t) {
        int yy = hh + (t / 3 - 1) * d;
        int xx = ww + (t % 3 - 1) * d;
        float s = 0.f;
        if (yy >= 0 && yy < HH && xx >= 0 && xx < WW) {
            const uint4* kp = (const uint4*)(
                qkvb + (size_t)(b * NPIX + yy * WW + xx) * QKVC + 256 + obase);
            float kv[32];
            #pragma unroll
            for (int m4 = 0; m4 < 4; ++m4) unpack8(kp[m4], kv + 8 * m4);
            #pragma unroll
            for (int hd = 0; hd < 32; ++hd) s += q[hd] * kv[hd];
        }
        sc[t] = s * SCALE;             // OOB -> exactly 0, stays in softmax denom
    }
    float m = sc[0];
    #pragma unroll
    for (int t = 1; t < 9; ++t) m = fmaxf(m, sc[t]);
    float sum = 0.f;
    #pragma unroll
    for (int t = 0; t < 9; ++t) { sc[t] = __expf(sc[t] - m); sum += sc[t]; }
    const float inv = 1.f / sum;

    float o[32];
    #pragma unroll
    for (int hd = 0; hd < 32; ++hd) o[hd] = 0.f;
    #pragma unroll
    for (int t = 0; t < 9; ++t) {
        int yy = hh + (t / 3 - 1) * d;
        int xx = ww + (t % 3 - 1) * d;
        if (yy >= 0 && yy < HH && xx >= 0 && xx < WW) {
            const uint4* vp = (const uint4*)(
                qkvb + (size_t)(b * NPIX + yy * WW + xx) * QKVC + 512 + obase);
            float vv[32];
            #pragma unroll
            for (int m4 = 0; m4 < 4; ++m4) unpack8(vp[m4], vv + 8 * m4);
            float wgt = sc[t] * inv;
            #pragma unroll
            for (int hd = 0; hd < 32; ++hd) o[hd] += wgt * vv[hd];
        }
    }
    uint4* xp = (uint4*)(Xb + (size_t)n * CDIM + obase);
    #pragma unroll
    for (int m4 = 0; m4 < 4; ++m4) {
        uint4 v;
        v.x = f2b(o[8 * m4 + 0]) | ((uint)f2b(o[8 * m4 + 1]) << 16);
        v.y = f2b(o[8 * m4 + 2]) | ((uint)f2b(o[8 * m4 + 3]) << 16);
        v.z = f2b(o[8 * m4 + 4]) | ((uint)f2b(o[8 * m4 + 5]) << 16);
        v.w = f2b(o[8 * m4 + 6]) | ((uint)f2b(o[8 * m4 + 7]) << 16);
        xp[m4] = v;
    }
}

// ---------------------------------------------------------------------------
// MFMA NT GEMM + epilogue: out[n][co] = Xb·Wpb^T + bias + Y residual (fp32 out)
// ---------------------------------------------------------------------------
__global__ __launch_bounds__(256) void proj_mfma(
    const ushort* __restrict__ Xb, const ushort* __restrict__ Wpb,
    const float* __restrict__ bp, const ushort* __restrict__ Yb,
    float* __restrict__ out)
{
    __shared__ __align__(16) ushort As[128 * 40];
    __shared__ __align__(16) ushort Bs[128 * 40];
    const int tid = threadIdx.x;
    const int lane = tid & 63;
    const int wave = tid >> 6;
    const int wr = wave >> 1, wc = wave & 1;
    const int l15 = lane & 15, quad = lane >> 4;
    const int n0 = blockIdx.x * 128;
    const int o0 = blockIdx.y * 128;

    const int sm = tid >> 2;
    const int sk = (tid & 3) * 8;

    floatx4 acc[4][4] = {};

    for (int k0 = 0; k0 < CDIM; k0 += 32) {
        #pragma unroll
        for (int p = 0; p < 2; ++p) {
            int m = sm + p * 64;
            *(uint4*)(&As[m * 40 + sk]) =
                *(const uint4*)(&Xb[(size_t)(n0 + m) * CDIM + k0 + sk]);
            *(uint4*)(&Bs[m * 40 + sk]) =
                *(const uint4*)(&Wpb[(size_t)(o0 + m) * CDIM + k0 + sk]);
        }
        __syncthreads();
        short8 af[4], bfr[4];
        #pragma unroll
        for (int i = 0; i < 4; ++i)
            af[i] = *(const short8*)(&As[(wr * 64 + i * 16 + l15) * 40 + quad * 8]);
        #pragma unroll
        for (int j = 0; j < 4; ++j)
            bfr[j] = *(const short8*)(&Bs[(wc * 64 + j * 16 + l15) * 40 + quad * 8]);
        #pragma unroll
        for (int i = 0; i < 4; ++i)
            #pragma unroll
            for (int j = 0; j < 4; ++j)
                acc[i][j] = __builtin_amdgcn_mfma_f32_16x16x32_bf16(
                    af[i], bfr[j], acc[i][j], 0, 0, 0);
        __syncthreads();
    }
    #pragma unroll
    for (int i = 0; i < 4; ++i)
        #pragma unroll
        for (int j = 0; j < 4; ++j) {
            int o = o0 + wc * 64 + j * 16 + l15;
            float bias = bp[o];
            #pragma unroll
            for (int r = 0; r < 4; ++r) {
                int n = n0 + wr * 64 + i * 16 + quad * 4 + r;
                out[(size_t)n * CDIM + o] =
                    acc[i][j][r] + bias + b2f(Yb[(size_t)n * CDIM + o]);
            }
        }
}

extern "C" void kernel_launch(void* const* d_in, const int* in_sizes, int n_in,
                              void* d_out, int out_size, void* d_ws, size_t ws_size,
                              hipStream_t stream) {
    const float* rgb    = (const float*)d_in[0];
    const float* ir     = (const float*)d_in[1];
    const float* w_qkv  = (const float*)d_in[2];
    const float* w_proj = (const float*)d_in[3];
    const float* b_proj = (const float*)d_in[4];
    float* out = (float*)d_out;

    ushort* qkvb = (ushort*)d_ws;                    // 25600*768  = 39.3 MB
    ushort* Yb   = qkvb + (size_t)BN * QKVC;         // 25600*256  = 13.1 MB
    ushort* Xb   = Yb + (size_t)BN * CDIM;           // 25600*256  = 13.1 MB
    ushort* Wqb  = Xb + (size_t)BN * CDIM;           // 768*256
    ushort* Wpb  = Wqb + (size_t)QKVC * CDIM;        // 256*256

    cast_w_k<<<QKVC, 256, 0, stream>>>(w_qkv, w_proj, Wqb, Wpb);
    cast_y_k<<<dim3(NPIX / 64, CDIM / 32, NB), 256, 0, stream>>>(rgb, ir, Yb);
    gemm_qkv_mfma<<<dim3(BN / 128, QKVC / 128), 256, 0, stream>>>(Yb, Wqb, qkvb);
    attn_k<<<dim3(NPIX / 256, 8, NB), 256, 0, stream>>>(qkvb, Xb);
    proj_mfma<<<dim3(BN / 128, CDIM / 128), 256, 0, stream>>>(Xb, Wpb, b_proj, Yb, out);
}

// Round 3
// 157.990 us; speedup vs baseline: 2.0899x; 1.1269x over previous
//
#include <hip/hip_runtime.h>

#define HH 80
#define WW 80
#define NPIX 6400          // 80*80
#define NB 4
#define BN 25600           // NB * NPIX
#define CDIM 256
#define QKVC 768
#define SCALE 0.17677669529663689f   // 32^-0.5

typedef __attribute__((ext_vector_type(8))) short short8;
typedef __attribute__((ext_vector_type(4))) float floatx4;

__device__ __forceinline__ float b2f(ushort u) {
    return __uint_as_float(((uint)u) << 16);
}
__device__ __forceinline__ ushort f2b(float f) {
    uint u = __float_as_uint(f);
    return (ushort)((u + 0x7fffu + ((u >> 16) & 1u)) >> 16);   // RNE
}
__device__ __forceinline__ void unpack8(uint4 v, float* f) {
    f[0] = __uint_as_float(v.x << 16); f[1] = __uint_as_float(v.x & 0xffff0000u);
    f[2] = __uint_as_float(v.y << 16); f[3] = __uint_as_float(v.y & 0xffff0000u);
    f[4] = __uint_as_float(v.z << 16); f[5] = __uint_as_float(v.z & 0xffff0000u);
    f[6] = __uint_as_float(v.w << 16); f[7] = __uint_as_float(v.w & 0xffff0000u);
}
__device__ __forceinline__ void gload_lds16(const void* gptr, void* lptr) {
    __builtin_amdgcn_global_load_lds(
        (const __attribute__((address_space(1))) unsigned int*)gptr,
        (__attribute__((address_space(3))) unsigned int*)lptr,
        16, 0, 0);
}

// ---------------------------------------------------------------------------
// Cast both weight matrices to bf16 (layout unchanged: [o][c], c contiguous).
// ---------------------------------------------------------------------------
__global__ __launch_bounds__(256) void cast_w_k(
    const float* __restrict__ wq, const float* __restrict__ wp,
    ushort* __restrict__ wqb, ushort* __restrict__ wpb)
{
    int i = blockIdx.x * 256 + threadIdx.x;
    if (i < QKVC * CDIM) wqb[i] = f2b(wq[i]);
    if (i < CDIM * CDIM) wpb[i] = f2b(wp[i]);
}

// ---------------------------------------------------------------------------
// Yb[n][c] = bf16(concat(rgb, ir))  — transpose BCHW -> [n][c] via LDS tile.
// ---------------------------------------------------------------------------
__global__ __launch_bounds__(256) void cast_y_k(
    const float* __restrict__ rgb, const float* __restrict__ ir,
    ushort* __restrict__ Yb)
{
    __shared__ ushort T[32][72];
    const int tid = threadIdx.x;
    const int pix0 = blockIdx.x * 64;
    const int cb = blockIdx.y;
    const int b = blockIdx.z;

    const int pl = tid & 63, cg = tid >> 6;
    #pragma unroll
    for (int cc = 0; cc < 32; cc += 4) {
        int c = cb * 32 + cc + cg;
        const float* src = (c < 128) ? (rgb + ((size_t)b * 128 + c) * NPIX)
                                     : (ir + ((size_t)b * 128 + (c - 128)) * NPIX);
        T[cc + cg][pl] = f2b(src[pix0 + pl]);
    }
    __syncthreads();
    const int nl = tid >> 2, c0 = (tid & 3) * 8;
    ushort tmp[8];
    #pragma unroll
    for (int j = 0; j < 8; ++j) tmp[j] = T[c0 + j][nl];
    uint4 v;
    v.x = tmp[0] | ((uint)tmp[1] << 16);
    v.y = tmp[2] | ((uint)tmp[3] << 16);
    v.z = tmp[4] | ((uint)tmp[5] << 16);
    v.w = tmp[6] | ((uint)tmp[7] << 16);
    *(uint4*)(&Yb[((size_t)(b * NPIX + pix0 + nl)) * CDIM + cb * 32 + c0]) = v;
}

// ---------------------------------------------------------------------------
// MFMA NT GEMM: qkvb[n][o] = sum_c Yb[n][c] * Wqb[o][c], bf16 in/out, f32 acc.
// ---------------------------------------------------------------------------
__global__ __launch_bounds__(256) void gemm_qkv_mfma(
    const ushort* __restrict__ Yb, const ushort* __restrict__ Wb,
    ushort* __restrict__ qkvb)
{
    __shared__ __align__(16) ushort As[128 * 40];
    __shared__ __align__(16) ushort Bs[128 * 40];
    const int tid = threadIdx.x;
    const int lane = tid & 63;
    const int wave = tid >> 6;
    const int wr = wave >> 1, wc = wave & 1;
    const int l15 = lane & 15, quad = lane >> 4;
    const int n0 = blockIdx.x * 128;
    const int o0 = blockIdx.y * 128;

    const int sm = tid >> 2;
    const int sk = (tid & 3) * 8;

    floatx4 acc[4][4] = {};

    for (int k0 = 0; k0 < CDIM; k0 += 32) {
        #pragma unroll
        for (int p = 0; p < 2; ++p) {
            int m = sm + p * 64;
            *(uint4*)(&As[m * 40 + sk]) =
                *(const uint4*)(&Yb[(size_t)(n0 + m) * CDIM + k0 + sk]);
            *(uint4*)(&Bs[m * 40 + sk]) =
                *(const uint4*)(&Wb[(size_t)(o0 + m) * CDIM + k0 + sk]);
        }
        __syncthreads();
        short8 af[4], bfr[4];
        #pragma unroll
        for (int i = 0; i < 4; ++i)
            af[i] = *(const short8*)(&As[(wr * 64 + i * 16 + l15) * 40 + quad * 8]);
        #pragma unroll
        for (int j = 0; j < 4; ++j)
            bfr[j] = *(const short8*)(&Bs[(wc * 64 + j * 16 + l15) * 40 + quad * 8]);
        #pragma unroll
        for (int i = 0; i < 4; ++i)
            #pragma unroll
            for (int j = 0; j < 4; ++j)
                acc[i][j] = __builtin_amdgcn_mfma_f32_16x16x32_bf16(
                    af[i], bfr[j], acc[i][j], 0, 0, 0);
        __syncthreads();
    }
    #pragma unroll
    for (int i = 0; i < 4; ++i)
        #pragma unroll
        for (int j = 0; j < 4; ++j)
            #pragma unroll
            for (int r = 0; r < 4; ++r) {
                int n = n0 + wr * 64 + i * 16 + quad * 4 + r;
                int o = o0 + wc * 64 + j * 16 + l15;
                qkvb[(size_t)n * QKVC + o] = f2b(acc[i][j][r]);
            }
}

// ---------------------------------------------------------------------------
// Tiled dilated local attention. One block = (b, dil, head) x 16x16 pixel tile.
// K/V halo region staged into LDS via global_load_lds (layout [c4][pix][16B]).
// OOB neighbors: staged clamped (value unused), masked at compute (score 0 in
// softmax denom per nn.Unfold zero-padding, value 0).
// ---------------------------------------------------------------------------
template<int D>
__device__ __forceinline__ void attn_tile(
    const ushort* __restrict__ qkvb, ushort* __restrict__ Xb,
    ushort* kl, ushort* vl, int b, int dil_i, int head, int y0, int x0)
{
    constexpr int RW = 16 + 2 * D;
    constexpr int RP = RW * RW;
    const int tid = threadIdx.x;
    const int lane = tid & 63;
    const int wave = tid >> 6;          // = channel chunk c (0..3)
    const int obase = dil_i * 128 + head * 32;

    // per-thread q load (independent of staging; overlaps)
    const int px = tid & 15, py = tid >> 4;
    const int n = b * NPIX + (y0 + py) * WW + (x0 + px);
    float q[32];
    {
        const uint4* qp = (const uint4*)(qkvb + (size_t)n * QKVC + obase);
        uint4 v0 = qp[0], v1 = qp[1], v2 = qp[2], v3 = qp[3];
        unpack8(v0, q); unpack8(v1, q + 8); unpack8(v2, q + 16); unpack8(v3, q + 24);
    }

    // stage K,V region: wave w loads channel-chunk w for all RP pixels
    for (int p0 = 0; p0 < RP; p0 += 64) {
        int p = p0 + lane;
        int ry = p / RW, rx = p % RW;               // compile-time RW
        int gy = min(max(y0 - D + ry, 0), HH - 1);  // clamp: valid address, value masked later
        int gx = min(max(x0 - D + rx, 0), WW - 1);
        const ushort* row = qkvb + (size_t)(b * NPIX + gy * WW + gx) * QKVC + obase + wave * 8;
        if (p < RP) {
            gload_lds16(row + 256, kl + (size_t)(wave * RP + p0) * 8);
            gload_lds16(row + 512, vl + (size_t)(wave * RP + p0) * 8);
        }
    }
    __syncthreads();

    float sc[9];
    #pragma unroll
    for (int t = 0; t < 9; ++t) {
        const int dy = t / 3 - 1, dx = t % 3 - 1;
        const int yy = y0 + py + dy * D, xx = x0 + px + dx * D;
        const int p = (py + D + dy * D) * RW + (px + D + dx * D);
        float s = 0.f;
        if (yy >= 0 && yy < HH && xx >= 0 && xx < WW) {
            #pragma unroll
            for (int c = 0; c < 4; ++c) {
                float kv[8];
                unpack8(*(const uint4*)(kl + (size_t)(c * RP + p) * 8), kv);
                #pragma unroll
                for (int j = 0; j < 8; ++j) s += q[c * 8 + j] * kv[j];
            }
        }
        sc[t] = s * SCALE;              // OOB stays exactly 0 (in softmax denom)
    }
    float m = sc[0];
    #pragma unroll
    for (int t = 1; t < 9; ++t) m = fmaxf(m, sc[t]);
    float sum = 0.f;
    #pragma unroll
    for (int t = 0; t < 9; ++t) { sc[t] = __expf(sc[t] - m); sum += sc[t]; }
    const float inv = 1.f / sum;

    float o[32];
    #pragma unroll
    for (int hd = 0; hd < 32; ++hd) o[hd] = 0.f;
    #pragma unroll
    for (int t = 0; t < 9; ++t) {
        const int dy = t / 3 - 1, dx = t % 3 - 1;
        const int yy = y0 + py + dy * D, xx = x0 + px + dx * D;
        const int p = (py + D + dy * D) * RW + (px + D + dx * D);
        if (yy >= 0 && yy < HH && xx >= 0 && xx < WW) {
            const float wgt = sc[t] * inv;
            #pragma unroll
            for (int c = 0; c < 4; ++c) {
                float vv[8];
                unpack8(*(const uint4*)(vl + (size_t)(c * RP + p) * 8), vv);
                #pragma unroll
                for (int j = 0; j < 8; ++j) o[c * 8 + j] += wgt * vv[j];
            }
        }
    }
    uint4* xp = (uint4*)(Xb + (size_t)n * CDIM + obase);
    #pragma unroll
    for (int m4 = 0; m4 < 4; ++m4) {
        uint4 v;
        v.x = f2b(o[8 * m4 + 0]) | ((uint)f2b(o[8 * m4 + 1]) << 16);
        v.y = f2b(o[8 * m4 + 2]) | ((uint)f2b(o[8 * m4 + 3]) << 16);
        v.z = f2b(o[8 * m4 + 4]) | ((uint)f2b(o[8 * m4 + 5]) << 16);
        v.w = f2b(o[8 * m4 + 6]) | ((uint)f2b(o[8 * m4 + 7]) << 16);
        xp[m4] = v;
    }
}

__global__ __launch_bounds__(256, 2) void attn2_k(
    const ushort* __restrict__ qkvb, ushort* __restrict__ Xb)
{
    __shared__ __align__(16) ushort kl[4 * 484 * 8];   // 31 KB (worst case d=3)
    __shared__ __align__(16) ushort vl[4 * 484 * 8];   // 31 KB
    const int tile = blockIdx.x;                       // 0..24
    const int y0 = (tile / 5) * 16, x0 = (tile % 5) * 16;
    const int dh = blockIdx.y;
    const int b = blockIdx.z;
    const int dil_i = dh >> 2, head = dh & 3;
    if (dil_i == 0) attn_tile<2>(qkvb, Xb, kl, vl, b, 0, head, y0, x0);
    else            attn_tile<3>(qkvb, Xb, kl, vl, b, 1, head, y0, x0);
}

// ---------------------------------------------------------------------------
// MFMA NT GEMM + epilogue: out[n][co] = Xb·Wpb^T + bias + Y residual (fp32 out)
// ---------------------------------------------------------------------------
__global__ __launch_bounds__(256) void proj_mfma(
    const ushort* __restrict__ Xb, const ushort* __restrict__ Wpb,
    const float* __restrict__ bp, const ushort* __restrict__ Yb,
    float* __restrict__ out)
{
    __shared__ __align__(16) ushort As[128 * 40];
    __shared__ __align__(16) ushort Bs[128 * 40];
    const int tid = threadIdx.x;
    const int lane = tid & 63;
    const int wave = tid >> 6;
    const int wr = wave >> 1, wc = wave & 1;
    const int l15 = lane & 15, quad = lane >> 4;
    const int n0 = blockIdx.x * 128;
    const int o0 = blockIdx.y * 128;

    const int sm = tid >> 2;
    const int sk = (tid & 3) * 8;

    floatx4 acc[4][4] = {};

    for (int k0 = 0; k0 < CDIM; k0 += 32) {
        #pragma unroll
        for (int p = 0; p < 2; ++p) {
            int m = sm + p * 64;
            *(uint4*)(&As[m * 40 + sk]) =
                *(const uint4*)(&Xb[(size_t)(n0 + m) * CDIM + k0 + sk]);
            *(uint4*)(&Bs[m * 40 + sk]) =
                *(const uint4*)(&Wpb[(size_t)(o0 + m) * CDIM + k0 + sk]);
        }
        __syncthreads();
        short8 af[4], bfr[4];
        #pragma unroll
        for (int i = 0; i < 4; ++i)
            af[i] = *(const short8*)(&As[(wr * 64 + i * 16 + l15) * 40 + quad * 8]);
        #pragma unroll
        for (int j = 0; j < 4; ++j)
            bfr[j] = *(const short8*)(&Bs[(wc * 64 + j * 16 + l15) * 40 + quad * 8]);
        #pragma unroll
        for (int i = 0; i < 4; ++i)
            #pragma unroll
            for (int j = 0; j < 4; ++j)
                acc[i][j] = __builtin_amdgcn_mfma_f32_16x16x32_bf16(
                    af[i], bfr[j], acc[i][j], 0, 0, 0);
        __syncthreads();
    }
    #pragma unroll
    for (int i = 0; i < 4; ++i)
        #pragma unroll
        for (int j = 0; j < 4; ++j) {
            int o = o0 + wc * 64 + j * 16 + l15;
            float bias = bp[o];
            #pragma unroll
            for (int r = 0; r < 4; ++r) {
                int n = n0 + wr * 64 + i * 16 + quad * 4 + r;
                out[(size_t)n * CDIM + o] =
                    acc[i][j][r] + bias + b2f(Yb[(size_t)n * CDIM + o]);
            }
        }
}

extern "C" void kernel_launch(void* const* d_in, const int* in_sizes, int n_in,
                              void* d_out, int out_size, void* d_ws, size_t ws_size,
                              hipStream_t stream) {
    const float* rgb    = (const float*)d_in[0];
    const float* ir     = (const float*)d_in[1];
    const float* w_qkv  = (const float*)d_in[2];
    const float* w_proj = (const float*)d_in[3];
    const float* b_proj = (const float*)d_in[4];
    float* out = (float*)d_out;

    ushort* qkvb = (ushort*)d_ws;                    // 25600*768  = 39.3 MB
    ushort* Yb   = qkvb + (size_t)BN * QKVC;         // 25600*256  = 13.1 MB
    ushort* Xb   = Yb + (size_t)BN * CDIM;           // 25600*256  = 13.1 MB
    ushort* Wqb  = Xb + (size_t)BN * CDIM;           // 768*256
    ushort* Wpb  = Wqb + (size_t)QKVC * CDIM;        // 256*256

    cast_w_k<<<QKVC, 256, 0, stream>>>(w_qkv, w_proj, Wqb, Wpb);
    cast_y_k<<<dim3(NPIX / 64, CDIM / 32, NB), 256, 0, stream>>>(rgb, ir, Yb);
    gemm_qkv_mfma<<<dim3(BN / 128, QKVC / 128), 256, 0, stream>>>(Yb, Wqb, qkvb);
    attn2_k<<<dim3(25, 8, NB), 256, 0, stream>>>(qkvb, Xb);
    proj_mfma<<<dim3(BN / 128, CDIM / 128), 256, 0, stream>>>(Xb, Wpb, b_proj, Yb, out);
}

// Round 4
// 149.909 us; speedup vs baseline: 2.2026x; 1.0539x over previous
//
#include <hip/hip_runtime.h>

#define HH 80
#define WW 80
#define NPIX 6400          // 80*80
#define NB 4
#define BN 25600           // NB * NPIX
#define CDIM 256
#define QKVC 768
#define SCALE 0.17677669529663689f   // 32^-0.5

typedef __attribute__((ext_vector_type(8))) short short8;
typedef __attribute__((ext_vector_type(4))) float floatx4;

__device__ __forceinline__ float b2f(ushort u) {
    return __uint_as_float(((uint)u) << 16);
}
__device__ __forceinline__ ushort f2b(float f) {
    uint u = __float_as_uint(f);
    return (ushort)((u + 0x7fffu + ((u >> 16) & 1u)) >> 16);   // RNE
}
__device__ __forceinline__ void unpack8(uint4 v, float* f) {
    f[0] = __uint_as_float(v.x << 16); f[1] = __uint_as_float(v.x & 0xffff0000u);
    f[2] = __uint_as_float(v.y << 16); f[3] = __uint_as_float(v.y & 0xffff0000u);
    f[4] = __uint_as_float(v.z << 16); f[5] = __uint_as_float(v.z & 0xffff0000u);
    f[6] = __uint_as_float(v.w << 16); f[7] = __uint_as_float(v.w & 0xffff0000u);
}
__device__ __forceinline__ void gload_lds16(const void* gptr, void* lptr) {
    __builtin_amdgcn_global_load_lds(
        (const __attribute__((address_space(1))) unsigned int*)gptr,
        (__attribute__((address_space(3))) unsigned int*)lptr,
        16, 0, 0);
}

// ---------------------------------------------------------------------------
// Cast both weight matrices to bf16 (layout unchanged: [o][c], c contiguous).
// ---------------------------------------------------------------------------
__global__ __launch_bounds__(256) void cast_w_k(
    const float* __restrict__ wq, const float* __restrict__ wp,
    ushort* __restrict__ wqb, ushort* __restrict__ wpb)
{
    int i = blockIdx.x * 256 + threadIdx.x;
    if (i < QKVC * CDIM) wqb[i] = f2b(wq[i]);
    if (i < CDIM * CDIM) wpb[i] = f2b(wp[i]);
}

// ---------------------------------------------------------------------------
// Yb[n][c] = bf16(concat(rgb, ir))  — transpose BCHW -> [n][c] via LDS tile.
// ---------------------------------------------------------------------------
__global__ __launch_bounds__(256) void cast_y_k(
    const float* __restrict__ rgb, const float* __restrict__ ir,
    ushort* __restrict__ Yb)
{
    __shared__ ushort T[32][72];
    const int tid = threadIdx.x;
    const int pix0 = blockIdx.x * 64;
    const int cb = blockIdx.y;
    const int b = blockIdx.z;

    const int pl = tid & 63, cg = tid >> 6;
    #pragma unroll
    for (int cc = 0; cc < 32; cc += 4) {
        int c = cb * 32 + cc + cg;
        const float* src = (c < 128) ? (rgb + ((size_t)b * 128 + c) * NPIX)
                                     : (ir + ((size_t)b * 128 + (c - 128)) * NPIX);
        T[cc + cg][pl] = f2b(src[pix0 + pl]);
    }
    __syncthreads();
    const int nl = tid >> 2, c0 = (tid & 3) * 8;
    ushort tmp[8];
    #pragma unroll
    for (int j = 0; j < 8; ++j) tmp[j] = T[c0 + j][nl];
    uint4 v;
    v.x = tmp[0] | ((uint)tmp[1] << 16);
    v.y = tmp[2] | ((uint)tmp[3] << 16);
    v.z = tmp[4] | ((uint)tmp[5] << 16);
    v.w = tmp[6] | ((uint)tmp[7] << 16);
    *(uint4*)(&Yb[((size_t)(b * NPIX + pix0 + nl)) * CDIM + cb * 32 + c0]) = v;
}

// ---------------------------------------------------------------------------
// m97-style MFMA NT GEMM: out[n][o] = sum_c A[n][c] * W[o][c].
// 128x128 tile, BK=32, unpadded LDS [m][k], global_load_lds width=16 staging.
// Staging map: element = tid*8 + p*2048 -> row=tid>>2 (+p*64), k=(tid&3)*8;
// LDS byte offset = tid*16 + p*4096 == wave-uniform base + lane*16.  [m97/m104]
// ---------------------------------------------------------------------------
__device__ __forceinline__ void gemm_nt_body(
    const ushort* __restrict__ A, const ushort* __restrict__ W,
    ushort* As, ushort* Bs, int n0, int o0, floatx4 acc[4][4])
{
    const int tid = threadIdx.x;
    const int lane = tid & 63;
    const int wave = tid >> 6;
    const int wr = wave >> 1, wc = wave & 1;
    const int l15 = lane & 15, quad = lane >> 4;

    const int srow = tid >> 2;          // 0..63
    const int sk   = (tid & 3) * 8;     // 0,8,16,24

    for (int k0 = 0; k0 < CDIM; k0 += 32) {
        #pragma unroll
        for (int p = 0; p < 2; ++p) {
            // wave-uniform LDS base (elements): wave*512 + p*2048
            gload_lds16(&A[(size_t)(n0 + p * 64 + srow) * CDIM + k0 + sk],
                        As + wave * 512 + p * 2048);
            gload_lds16(&W[(size_t)(o0 + p * 64 + srow) * CDIM + k0 + sk],
                        Bs + wave * 512 + p * 2048);
        }
        __syncthreads();
        short8 af[4], bfr[4];
        #pragma unroll
        for (int i = 0; i < 4; ++i)
            af[i] = *(const short8*)(&As[(wr * 64 + i * 16 + l15) * 32 + quad * 8]);
        #pragma unroll
        for (int j = 0; j < 4; ++j)
            bfr[j] = *(const short8*)(&Bs[(wc * 64 + j * 16 + l15) * 32 + quad * 8]);
        #pragma unroll
        for (int i = 0; i < 4; ++i)
            #pragma unroll
            for (int j = 0; j < 4; ++j)
                acc[i][j] = __builtin_amdgcn_mfma_f32_16x16x32_bf16(
                    af[i], bfr[j], acc[i][j], 0, 0, 0);
        __syncthreads();
    }
}

__global__ __launch_bounds__(256) void gemm_qkv_mfma(
    const ushort* __restrict__ Yb, const ushort* __restrict__ Wb,
    ushort* __restrict__ qkvb)
{
    __shared__ __align__(16) ushort As[128 * 32];
    __shared__ __align__(16) ushort Bs[128 * 32];
    const int tid = threadIdx.x;
    const int lane = tid & 63;
    const int wave = tid >> 6;
    const int wr = wave >> 1, wc = wave & 1;
    const int l15 = lane & 15, quad = lane >> 4;
    const int n0 = blockIdx.x * 128;
    const int o0 = blockIdx.y * 128;

    floatx4 acc[4][4] = {};
    gemm_nt_body(Yb, Wb, As, Bs, n0, o0, acc);

    #pragma unroll
    for (int i = 0; i < 4; ++i)
        #pragma unroll
        for (int j = 0; j < 4; ++j)
            #pragma unroll
            for (int r = 0; r < 4; ++r) {
                int n = n0 + wr * 64 + i * 16 + quad * 4 + r;
                int o = o0 + wc * 64 + j * 16 + l15;
                qkvb[(size_t)n * QKVC + o] = f2b(acc[i][j][r]);
            }
}

// ---------------------------------------------------------------------------
// Tiled dilated local attention, two-phase K/V staging through ONE 31 KB LDS
// buffer (5 blocks/CU). One block = (b, dil, head) x 16x16 pixel tile.
// OOB neighbors: staged clamped (value unused), masked at compute (score 0 in
// softmax denom per nn.Unfold zero-padding, value 0).
// ---------------------------------------------------------------------------
template<int D>
__device__ __forceinline__ void attn_tile(
    const ushort* __restrict__ qkvb, ushort* __restrict__ Xb,
    ushort* kl, int b, int dil_i, int head, int y0, int x0)
{
    constexpr int RW = 16 + 2 * D;
    constexpr int RP = RW * RW;
    const int tid = threadIdx.x;
    const int lane = tid & 63;
    const int wave = tid >> 6;          // = channel chunk c (0..3)
    const int obase = dil_i * 128 + head * 32;

    const int px = tid & 15, py = tid >> 4;
    const int n = b * NPIX + (y0 + py) * WW + (x0 + px);
    float q[32];
    {
        const uint4* qp = (const uint4*)(qkvb + (size_t)n * QKVC + obase);
        uint4 v0 = qp[0], v1 = qp[1], v2 = qp[2], v3 = qp[3];
        unpack8(v0, q); unpack8(v1, q + 8); unpack8(v2, q + 16); unpack8(v3, q + 24);
    }

    // phase 1: stage K region (wave w = channel chunk w)
    for (int p0 = 0; p0 < RP; p0 += 64) {
        int p = p0 + lane;
        int ry = p / RW, rx = p % RW;
        int gy = min(max(y0 - D + ry, 0), HH - 1);
        int gx = min(max(x0 - D + rx, 0), WW - 1);
        const ushort* row = qkvb + (size_t)(b * NPIX + gy * WW + gx) * QKVC + obase + wave * 8;
        if (p < RP)
            gload_lds16(row + 256, kl + (size_t)(wave * RP + p0) * 8);
    }
    __syncthreads();

    float sc[9];
    #pragma unroll
    for (int t = 0; t < 9; ++t) {
        const int dy = t / 3 - 1, dx = t % 3 - 1;
        const int yy = y0 + py + dy * D, xx = x0 + px + dx * D;
        const int p = (py + D + dy * D) * RW + (px + D + dx * D);
        float s = 0.f;
        if (yy >= 0 && yy < HH && xx >= 0 && xx < WW) {
            #pragma unroll
            for (int c = 0; c < 4; ++c) {
                float kv[8];
                unpack8(*(const uint4*)(kl + (size_t)(c * RP + p) * 8), kv);
                #pragma unroll
                for (int j = 0; j < 8; ++j) s += q[c * 8 + j] * kv[j];
            }
        }
        sc[t] = s * SCALE;              // OOB stays exactly 0 (in softmax denom)
    }
    float m = sc[0];
    #pragma unroll
    for (int t = 1; t < 9; ++t) m = fmaxf(m, sc[t]);
    float sum = 0.f;
    #pragma unroll
    for (int t = 0; t < 9; ++t) { sc[t] = __expf(sc[t] - m); sum += sc[t]; }
    const float inv = 1.f / sum;

    // phase 2: re-stage same buffer with V
    __syncthreads();
    for (int p0 = 0; p0 < RP; p0 += 64) {
        int p = p0 + lane;
        int ry = p / RW, rx = p % RW;
        int gy = min(max(y0 - D + ry, 0), HH - 1);
        int gx = min(max(x0 - D + rx, 0), WW - 1);
        const ushort* row = qkvb + (size_t)(b * NPIX + gy * WW + gx) * QKVC + obase + wave * 8;
        if (p < RP)
            gload_lds16(row + 512, kl + (size_t)(wave * RP + p0) * 8);
    }
    __syncthreads();

    float o[32];
    #pragma unroll
    for (int hd = 0; hd < 32; ++hd) o[hd] = 0.f;
    #pragma unroll
    for (int t = 0; t < 9; ++t) {
        const int dy = t / 3 - 1, dx = t % 3 - 1;
        const int yy = y0 + py + dy * D, xx = x0 + px + dx * D;
        const int p = (py + D + dy * D) * RW + (px + D + dx * D);
        if (yy >= 0 && yy < HH && xx >= 0 && xx < WW) {
            const float wgt = sc[t] * inv;
            #pragma unroll
            for (int c = 0; c < 4; ++c) {
                float vv[8];
                unpack8(*(const uint4*)(kl + (size_t)(c * RP + p) * 8), vv);
                #pragma unroll
                for (int j = 0; j < 8; ++j) o[c * 8 + j] += wgt * vv[j];
            }
        }
    }
    uint4* xp = (uint4*)(Xb + (size_t)n * CDIM + obase);
    #pragma unroll
    for (int m4 = 0; m4 < 4; ++m4) {
        uint4 v;
        v.x = f2b(o[8 * m4 + 0]) | ((uint)f2b(o[8 * m4 + 1]) << 16);
        v.y = f2b(o[8 * m4 + 2]) | ((uint)f2b(o[8 * m4 + 3]) << 16);
        v.z = f2b(o[8 * m4 + 4]) | ((uint)f2b(o[8 * m4 + 5]) << 16);
        v.w = f2b(o[8 * m4 + 6]) | ((uint)f2b(o[8 * m4 + 7]) << 16);
        xp[m4] = v;
    }
}

__global__ __launch_bounds__(256) void attn2_k(
    const ushort* __restrict__ qkvb, ushort* __restrict__ Xb)
{
    __shared__ __align__(16) ushort kl[4 * 484 * 8];   // 31 KB (worst case d=3)
    const int tile = blockIdx.x;                       // 0..24
    const int y0 = (tile / 5) * 16, x0 = (tile % 5) * 16;
    const int dh = blockIdx.y;
    const int b = blockIdx.z;
    const int dil_i = dh >> 2, head = dh & 3;
    if (dil_i == 0) attn_tile<2>(qkvb, Xb, kl, b, 0, head, y0, x0);
    else            attn_tile<3>(qkvb, Xb, kl, b, 1, head, y0, x0);
}

// ---------------------------------------------------------------------------
// MFMA NT GEMM + epilogue: out[n][co] = Xb·Wpb^T + bias + Y residual (fp32 out)
// ---------------------------------------------------------------------------
__global__ __launch_bounds__(256) void proj_mfma(
    const ushort* __restrict__ Xb, const ushort* __restrict__ Wpb,
    const float* __restrict__ bp, const ushort* __restrict__ Yb,
    float* __restrict__ out)
{
    __shared__ __align__(16) ushort As[128 * 32];
    __shared__ __align__(16) ushort Bs[128 * 32];
    const int tid = threadIdx.x;
    const int lane = tid & 63;
    const int wave = tid >> 6;
    const int wr = wave >> 1, wc = wave & 1;
    const int l15 = lane & 15, quad = lane >> 4;
    const int n0 = blockIdx.x * 128;
    const int o0 = blockIdx.y * 128;

    floatx4 acc[4][4] = {};
    gemm_nt_body(Xb, Wpb, As, Bs, n0, o0, acc);

    #pragma unroll
    for (int i = 0; i < 4; ++i)
        #pragma unroll
        for (int j = 0; j < 4; ++j) {
            int o = o0 + wc * 64 + j * 16 + l15;
            float bias = bp[o];
            #pragma unroll
            for (int r = 0; r < 4; ++r) {
                int n = n0 + wr * 64 + i * 16 + quad * 4 + r;
                out[(size_t)n * CDIM + o] =
                    acc[i][j][r] + bias + b2f(Yb[(size_t)n * CDIM + o]);
            }
        }
}

extern "C" void kernel_launch(void* const* d_in, const int* in_sizes, int n_in,
                              void* d_out, int out_size, void* d_ws, size_t ws_size,
                              hipStream_t stream) {
    const float* rgb    = (const float*)d_in[0];
    const float* ir     = (const float*)d_in[1];
    const float* w_qkv  = (const float*)d_in[2];
    const float* w_proj = (const float*)d_in[3];
    const float* b_proj = (const float*)d_in[4];
    float* out = (float*)d_out;

    ushort* qkvb = (ushort*)d_ws;                    // 25600*768  = 39.3 MB
    ushort* Yb   = qkvb + (size_t)BN * QKVC;         // 25600*256  = 13.1 MB
    ushort* Xb   = Yb + (size_t)BN * CDIM;           // 25600*256  = 13.1 MB
    ushort* Wqb  = Xb + (size_t)BN * CDIM;           // 768*256
    ushort* Wpb  = Wqb + (size_t)QKVC * CDIM;        // 256*256

    cast_w_k<<<QKVC, 256, 0, stream>>>(w_qkv, w_proj, Wqb, Wpb);
    cast_y_k<<<dim3(NPIX / 64, CDIM / 32, NB), 256, 0, stream>>>(rgb, ir, Yb);
    gemm_qkv_mfma<<<dim3(BN / 128, QKVC / 128), 256, 0, stream>>>(Yb, Wqb, qkvb);
    attn2_k<<<dim3(25, 8, NB), 256, 0, stream>>>(qkvb, Xb);
    proj_mfma<<<dim3(BN / 128, CDIM / 128), 256, 0, stream>>>(Xb, Wpb, b_proj, Yb, out);
}

// Round 5
// 139.952 us; speedup vs baseline: 2.3593x; 1.0712x over previous
//
#include <hip/hip_runtime.h>

#define HH 80
#define WW 80
#define NPIX 6400          // 80*80
#define NB 4
#define BN 25600           // NB * NPIX
#define CDIM 256
#define QKVC 768
#define SCALE 0.17677669529663689f   // 32^-0.5

typedef __attribute__((ext_vector_type(8))) short short8;
typedef __attribute__((ext_vector_type(4))) float floatx4;

__device__ __forceinline__ float b2f(ushort u) {
    return __uint_as_float(((uint)u) << 16);
}
__device__ __forceinline__ ushort f2b(float f) {
    uint u = __float_as_uint(f);
    return (ushort)((u + 0x7fffu + ((u >> 16) & 1u)) >> 16);   // RNE
}
__device__ __forceinline__ void unpack8(uint4 v, float* f) {
    f[0] = __uint_as_float(v.x << 16); f[1] = __uint_as_float(v.x & 0xffff0000u);
    f[2] = __uint_as_float(v.y << 16); f[3] = __uint_as_float(v.y & 0xffff0000u);
    f[4] = __uint_as_float(v.z << 16); f[5] = __uint_as_float(v.z & 0xffff0000u);
    f[6] = __uint_as_float(v.w << 16); f[7] = __uint_as_float(v.w & 0xffff0000u);
}
__device__ __forceinline__ void gload_lds16(const void* gptr, void* lptr) {
    __builtin_amdgcn_global_load_lds(
        (const __attribute__((address_space(1))) unsigned int*)gptr,
        (__attribute__((address_space(3))) unsigned int*)lptr,
        16, 0, 0);
}

// ---------------------------------------------------------------------------
// Fused cast kernel.
//  blocks x <  100: Yb[n][c] = bf16(concat(rgb, ir)) via LDS transpose tile
//  blocks x >= 100: cast w_qkv / w_proj to bf16 (flat)
// ---------------------------------------------------------------------------
__global__ __launch_bounds__(256) void cast_all_k(
    const float* __restrict__ rgb, const float* __restrict__ ir,
    const float* __restrict__ wq, const float* __restrict__ wp,
    ushort* __restrict__ Yb, ushort* __restrict__ wqb, ushort* __restrict__ wpb)
{
    const int tid = threadIdx.x;
    if (blockIdx.x >= 100) {
        int i = (((blockIdx.x - 100) * 8 + blockIdx.y) * 4 + blockIdx.z) * 256 + tid;
        if (i < QKVC * CDIM) wqb[i] = f2b(wq[i]);
        else                 wpb[i - QKVC * CDIM] = f2b(wp[i - QKVC * CDIM]);
        return;
    }
    __shared__ ushort T[32][72];
    const int pix0 = blockIdx.x * 64;
    const int cb = blockIdx.y;
    const int b = blockIdx.z;

    const int pl = tid & 63, cg = tid >> 6;
    #pragma unroll
    for (int cc = 0; cc < 32; cc += 4) {
        int c = cb * 32 + cc + cg;
        const float* src = (c < 128) ? (rgb + ((size_t)b * 128 + c) * NPIX)
                                     : (ir + ((size_t)b * 128 + (c - 128)) * NPIX);
        T[cc + cg][pl] = f2b(src[pix0 + pl]);
    }
    __syncthreads();
    const int nl = tid >> 2, c0 = (tid & 3) * 8;
    ushort tmp[8];
    #pragma unroll
    for (int j = 0; j < 8; ++j) tmp[j] = T[c0 + j][nl];
    uint4 v;
    v.x = tmp[0] | ((uint)tmp[1] << 16);
    v.y = tmp[2] | ((uint)tmp[3] << 16);
    v.z = tmp[4] | ((uint)tmp[5] << 16);
    v.w = tmp[6] | ((uint)tmp[7] << 16);
    *(uint4*)(&Yb[((size_t)(b * NPIX + pix0 + nl)) * CDIM + cb * 32 + c0]) = v;
}

// ---------------------------------------------------------------------------
// m97-style MFMA NT GEMM body (A rows [*][CDIM]): 128x128 tile, BK=32,
// unpadded LDS [m][k], global_load_lds width=16 staging.
// Staging map: LDS elem = tid*8 + p*2048 == wave-uniform base + lane*16B. [m97/m104]
// ---------------------------------------------------------------------------
__device__ __forceinline__ void gemm_nt_body(
    const ushort* __restrict__ A, const ushort* __restrict__ W,
    ushort* As, ushort* Bs, int n0, int o0, floatx4 acc[4][4])
{
    const int tid = threadIdx.x;
    const int lane = tid & 63;
    const int wave = tid >> 6;
    const int wr = wave >> 1, wc = wave & 1;
    const int l15 = lane & 15, quad = lane >> 4;

    const int srow = tid >> 2;          // 0..63
    const int sk   = (tid & 3) * 8;     // 0,8,16,24

    for (int k0 = 0; k0 < CDIM; k0 += 32) {
        #pragma unroll
        for (int p = 0; p < 2; ++p) {
            gload_lds16(&A[(size_t)(n0 + p * 64 + srow) * CDIM + k0 + sk],
                        As + wave * 512 + p * 2048);
            gload_lds16(&W[(size_t)(o0 + p * 64 + srow) * CDIM + k0 + sk],
                        Bs + wave * 512 + p * 2048);
        }
        __syncthreads();
        short8 af[4], bfr[4];
        #pragma unroll
        for (int i = 0; i < 4; ++i)
            af[i] = *(const short8*)(&As[(wr * 64 + i * 16 + l15) * 32 + quad * 8]);
        #pragma unroll
        for (int j = 0; j < 4; ++j)
            bfr[j] = *(const short8*)(&Bs[(wc * 64 + j * 16 + l15) * 32 + quad * 8]);
        #pragma unroll
        for (int i = 0; i < 4; ++i)
            #pragma unroll
            for (int j = 0; j < 4; ++j)
                acc[i][j] = __builtin_amdgcn_mfma_f32_16x16x32_bf16(
                    af[i], bfr[j], acc[i][j], 0, 0, 0);
        __syncthreads();
    }
}

// ---------------------------------------------------------------------------
// QKV GEMM. Output layout: chunk-major qkv2[chunk][n][32], chunk = o>>5
// (chunk 0..7 = Q(dil,head), 8..15 = K, 16..23 = V).
// ---------------------------------------------------------------------------
__global__ __launch_bounds__(256) void gemm_qkv_mfma(
    const ushort* __restrict__ Yb, const ushort* __restrict__ Wb,
    ushort* __restrict__ qkv2)
{
    __shared__ __align__(16) ushort As[128 * 32];
    __shared__ __align__(16) ushort Bs[128 * 32];
    const int tid = threadIdx.x;
    const int lane = tid & 63;
    const int wave = tid >> 6;
    const int wr = wave >> 1, wc = wave & 1;
    const int l15 = lane & 15, quad = lane >> 4;
    const int n0 = blockIdx.x * 128;
    const int o0 = blockIdx.y * 128;

    floatx4 acc[4][4] = {};
    gemm_nt_body(Yb, Wb, As, Bs, n0, o0, acc);

    #pragma unroll
    for (int i = 0; i < 4; ++i)
        #pragma unroll
        for (int j = 0; j < 4; ++j) {
            const int o = o0 + wc * 64 + j * 16 + l15;
            ushort* cbase = qkv2 + (size_t)(o >> 5) * BN * 32 + (o & 31);
            #pragma unroll
            for (int r = 0; r < 4; ++r) {
                int n = n0 + wr * 64 + i * 16 + quad * 4 + r;
                cbase[(size_t)n * 32] = f2b(acc[i][j][r]);
            }
        }
}

// ---------------------------------------------------------------------------
// Tiled dilated local attention, two-phase K/V staging through ONE 31 KB LDS
// buffer. One block = (b, dil, head) x 16x16 pixel tile. Chunk-major qkv2:
// q loads wave-contiguous, staging lanes 64 B apart (2 lanes/128B line).
// OOB neighbors: staged clamped (value unused), masked at compute (score 0 in
// softmax denom per nn.Unfold zero-padding, value 0).
// ---------------------------------------------------------------------------
template<int D>
__device__ __forceinline__ void attn_tile(
    const ushort* __restrict__ qkv2, ushort* __restrict__ X2,
    ushort* kl, int b, int dh, int y0, int x0)
{
    constexpr int RW = 16 + 2 * D;
    constexpr int RP = RW * RW;
    const int tid = threadIdx.x;
    const int lane = tid & 63;
    const int wave = tid >> 6;          // = channel chunk c (0..3) for staging
    const ushort* Qc = qkv2 + (size_t)dh * BN * 32;
    const ushort* Kc = qkv2 + (size_t)(8 + dh) * BN * 32;
    const ushort* Vc = qkv2 + (size_t)(16 + dh) * BN * 32;

    const int px = tid & 15, py = tid >> 4;
    const int n = b * NPIX + (y0 + py) * WW + (x0 + px);
    float q[32];
    {
        const uint4* qp = (const uint4*)(Qc + (size_t)n * 32);
        uint4 v0 = qp[0], v1 = qp[1], v2 = qp[2], v3 = qp[3];
        unpack8(v0, q); unpack8(v1, q + 8); unpack8(v2, q + 16); unpack8(v3, q + 24);
    }

    // phase 1: stage K region (wave w = channel chunk w; LDS [c][p][16B])
    for (int p0 = 0; p0 < RP; p0 += 64) {
        int p = p0 + lane;
        int ry = p / RW, rx = p % RW;
        int gy = min(max(y0 - D + ry, 0), HH - 1);
        int gx = min(max(x0 - D + rx, 0), WW - 1);
        if (p < RP)
            gload_lds16(Kc + (size_t)(b * NPIX + gy * WW + gx) * 32 + wave * 8,
                        kl + (size_t)(wave * RP + p0) * 8);
    }
    __syncthreads();

    float sc[9];
    #pragma unroll
    for (int t = 0; t < 9; ++t) {
        const int dy = t / 3 - 1, dx = t % 3 - 1;
        const int yy = y0 + py + dy * D, xx = x0 + px + dx * D;
        const int p = (py + D + dy * D) * RW + (px + D + dx * D);
        float s = 0.f;
        if (yy >= 0 && yy < HH && xx >= 0 && xx < WW) {
            #pragma unroll
            for (int c = 0; c < 4; ++c) {
                float kv[8];
                unpack8(*(const uint4*)(kl + (size_t)(c * RP + p) * 8), kv);
                #pragma unroll
                for (int j = 0; j < 8; ++j) s += q[c * 8 + j] * kv[j];
            }
        }
        sc[t] = s * SCALE;              // OOB stays exactly 0 (in softmax denom)
    }
    float m = sc[0];
    #pragma unroll
    for (int t = 1; t < 9; ++t) m = fmaxf(m, sc[t]);
    float sum = 0.f;
    #pragma unroll
    for (int t = 0; t < 9; ++t) { sc[t] = __expf(sc[t] - m); sum += sc[t]; }
    const float inv = 1.f / sum;

    // phase 2: re-stage same buffer with V
    __syncthreads();
    for (int p0 = 0; p0 < RP; p0 += 64) {
        int p = p0 + lane;
        int ry = p / RW, rx = p % RW;
        int gy = min(max(y0 - D + ry, 0), HH - 1);
        int gx = min(max(x0 - D + rx, 0), WW - 1);
        if (p < RP)
            gload_lds16(Vc + (size_t)(b * NPIX + gy * WW + gx) * 32 + wave * 8,
                        kl + (size_t)(wave * RP + p0) * 8);
    }
    __syncthreads();

    float o[32];
    #pragma unroll
    for (int hd = 0; hd < 32; ++hd) o[hd] = 0.f;
    #pragma unroll
    for (int t = 0; t < 9; ++t) {
        const int dy = t / 3 - 1, dx = t % 3 - 1;
        const int yy = y0 + py + dy * D, xx = x0 + px + dx * D;
        const int p = (py + D + dy * D) * RW + (px + D + dx * D);
        if (yy >= 0 && yy < HH && xx >= 0 && xx < WW) {
            const float wgt = sc[t] * inv;
            #pragma unroll
            for (int c = 0; c < 4; ++c) {
                float vv[8];
                unpack8(*(const uint4*)(kl + (size_t)(c * RP + p) * 8), vv);
                #pragma unroll
                for (int j = 0; j < 8; ++j) o[c * 8 + j] += wgt * vv[j];
            }
        }
    }
    uint4* xp = (uint4*)(X2 + (size_t)dh * BN * 32 + (size_t)n * 32);
    #pragma unroll
    for (int m4 = 0; m4 < 4; ++m4) {
        uint4 v;
        v.x = f2b(o[8 * m4 + 0]) | ((uint)f2b(o[8 * m4 + 1]) << 16);
        v.y = f2b(o[8 * m4 + 2]) | ((uint)f2b(o[8 * m4 + 3]) << 16);
        v.z = f2b(o[8 * m4 + 4]) | ((uint)f2b(o[8 * m4 + 5]) << 16);
        v.w = f2b(o[8 * m4 + 6]) | ((uint)f2b(o[8 * m4 + 7]) << 16);
        xp[m4] = v;
    }
}

__global__ __launch_bounds__(256) void attn2_k(
    const ushort* __restrict__ qkv2, ushort* __restrict__ X2)
{
    __shared__ __align__(16) ushort kl[4 * 484 * 8];   // 31 KB (worst case d=3)
    const int tile = blockIdx.x;                       // 0..24
    const int y0 = (tile / 5) * 16, x0 = (tile % 5) * 16;
    const int dh = blockIdx.y;                         // dil*4 + head
    const int b = blockIdx.z;
    if (dh < 4) attn_tile<2>(qkv2, X2, kl, b, dh, y0, x0);
    else        attn_tile<3>(qkv2, X2, kl, b, dh, y0, x0);
}

// ---------------------------------------------------------------------------
// MFMA NT GEMM + epilogue: out[n][co] = X·Wp^T + bias + Y residual (fp32 out).
// A staged chunk-wise from X2 (k0-chunk == dh chunk): fully contiguous.
// ---------------------------------------------------------------------------
__global__ __launch_bounds__(256) void proj_mfma(
    const ushort* __restrict__ X2, const ushort* __restrict__ Wpb,
    const float* __restrict__ bp, const ushort* __restrict__ Yb,
    float* __restrict__ out)
{
    __shared__ __align__(16) ushort As[128 * 32];
    __shared__ __align__(16) ushort Bs[128 * 32];
    const int tid = threadIdx.x;
    const int lane = tid & 63;
    const int wave = tid >> 6;
    const int wr = wave >> 1, wc = wave & 1;
    const int l15 = lane & 15, quad = lane >> 4;
    const int n0 = blockIdx.x * 128;
    const int o0 = blockIdx.y * 128;

    const int srow = tid >> 2;
    const int sk   = (tid & 3) * 8;

    floatx4 acc[4][4] = {};

    for (int k0 = 0; k0 < CDIM; k0 += 32) {
        const ushort* Achunk = X2 + (size_t)(k0 >> 5) * BN * 32;
        #pragma unroll
        for (int p = 0; p < 2; ++p) {
            gload_lds16(&Achunk[(size_t)(n0 + p * 64 + srow) * 32 + sk],
                        As + wave * 512 + p * 2048);
            gload_lds16(&Wpb[(size_t)(o0 + p * 64 + srow) * CDIM + k0 + sk],
                        Bs + wave * 512 + p * 2048);
        }
        __syncthreads();
        short8 af[4], bfr[4];
        #pragma unroll
        for (int i = 0; i < 4; ++i)
            af[i] = *(const short8*)(&As[(wr * 64 + i * 16 + l15) * 32 + quad * 8]);
        #pragma unroll
        for (int j = 0; j < 4; ++j)
            bfr[j] = *(const short8*)(&Bs[(wc * 64 + j * 16 + l15) * 32 + quad * 8]);
        #pragma unroll
        for (int i = 0; i < 4; ++i)
            #pragma unroll
            for (int j = 0; j < 4; ++j)
                acc[i][j] = __builtin_amdgcn_mfma_f32_16x16x32_bf16(
                    af[i], bfr[j], acc[i][j], 0, 0, 0);
        __syncthreads();
    }

    #pragma unroll
    for (int i = 0; i < 4; ++i)
        #pragma unroll
        for (int j = 0; j < 4; ++j) {
            int o = o0 + wc * 64 + j * 16 + l15;
            float bias = bp[o];
            #pragma unroll
            for (int r = 0; r < 4; ++r) {
                int n = n0 + wr * 64 + i * 16 + quad * 4 + r;
                out[(size_t)n * CDIM + o] =
                    acc[i][j][r] + bias + b2f(Yb[(size_t)n * CDIM + o]);
            }
        }
}

extern "C" void kernel_launch(void* const* d_in, const int* in_sizes, int n_in,
                              void* d_out, int out_size, void* d_ws, size_t ws_size,
                              hipStream_t stream) {
    const float* rgb    = (const float*)d_in[0];
    const float* ir     = (const float*)d_in[1];
    const float* w_qkv  = (const float*)d_in[2];
    const float* w_proj = (const float*)d_in[3];
    const float* b_proj = (const float*)d_in[4];
    float* out = (float*)d_out;

    ushort* qkv2 = (ushort*)d_ws;                    // 24 chunks * 25600*32 = 39.3 MB
    ushort* Yb   = qkv2 + (size_t)24 * BN * 32;      // 25600*256 = 13.1 MB
    ushort* X2   = Yb + (size_t)BN * CDIM;           // 8 chunks * 25600*32 = 13.1 MB
    ushort* Wqb  = X2 + (size_t)8 * BN * 32;         // 768*256
    ushort* Wpb  = Wqb + (size_t)QKVC * CDIM;        // 256*256

    cast_all_k<<<dim3(132, 8, NB), 256, 0, stream>>>(rgb, ir, w_qkv, w_proj,
                                                     Yb, Wqb, Wpb);
    gemm_qkv_mfma<<<dim3(BN / 128, QKVC / 128), 256, 0, stream>>>(Yb, Wqb, qkv2);
    attn2_k<<<dim3(25, 8, NB), 256, 0, stream>>>(qkv2, X2);
    proj_mfma<<<dim3(BN / 128, CDIM / 128), 256, 0, stream>>>(X2, Wpb, b_proj, Yb, out);
}

// Round 6
// 136.008 us; speedup vs baseline: 2.4277x; 1.0290x over previous
//
#include <hip/hip_runtime.h>

#define HH 80
#define WW 80
#define NPIX 6400          // 80*80
#define NB 4
#define BN 25600           // NB * NPIX
#define CDIM 256
#define QKVC 768
#define SCALE 0.17677669529663689f   // 32^-0.5

typedef __attribute__((ext_vector_type(8))) short short8;
typedef __attribute__((ext_vector_type(4))) float floatx4;

__device__ __forceinline__ float b2f(ushort u) {
    return __uint_as_float(((uint)u) << 16);
}
__device__ __forceinline__ ushort f2b(float f) {
    uint u = __float_as_uint(f);
    return (ushort)((u + 0x7fffu + ((u >> 16) & 1u)) >> 16);   // RNE
}
__device__ __forceinline__ void unpack8(uint4 v, float* f) {
    f[0] = __uint_as_float(v.x << 16); f[1] = __uint_as_float(v.x & 0xffff0000u);
    f[2] = __uint_as_float(v.y << 16); f[3] = __uint_as_float(v.y & 0xffff0000u);
    f[4] = __uint_as_float(v.z << 16); f[5] = __uint_as_float(v.z & 0xffff0000u);
    f[6] = __uint_as_float(v.w << 16); f[7] = __uint_as_float(v.w & 0xffff0000u);
}
__device__ __forceinline__ void gload_lds16(const void* gptr, void* lptr) {
    __builtin_amdgcn_global_load_lds(
        (const __attribute__((address_space(1))) unsigned int*)gptr,
        (__attribute__((address_space(3))) unsigned int*)lptr,
        16, 0, 0);
}

// ---------------------------------------------------------------------------
// Fused cast kernel.
//  blocks x <  100: Yb[n][c] = bf16(concat(rgb, ir)) via LDS transpose tile
//  blocks x >= 100: cast w_qkv / w_proj to bf16 (flat)
// ---------------------------------------------------------------------------
__global__ __launch_bounds__(256) void cast_all_k(
    const float* __restrict__ rgb, const float* __restrict__ ir,
    const float* __restrict__ wq, const float* __restrict__ wp,
    ushort* __restrict__ Yb, ushort* __restrict__ wqb, ushort* __restrict__ wpb)
{
    const int tid = threadIdx.x;
    if (blockIdx.x >= 100) {
        int i = (((blockIdx.x - 100) * 8 + blockIdx.y) * 4 + blockIdx.z) * 256 + tid;
        if (i < QKVC * CDIM) wqb[i] = f2b(wq[i]);
        else                 wpb[i - QKVC * CDIM] = f2b(wp[i - QKVC * CDIM]);
        return;
    }
    __shared__ ushort T[32][72];
    const int pix0 = blockIdx.x * 64;
    const int cb = blockIdx.y;
    const int b = blockIdx.z;

    const int pl = tid & 63, cg = tid >> 6;
    #pragma unroll
    for (int cc = 0; cc < 32; cc += 4) {
        int c = cb * 32 + cc + cg;
        const float* src = (c < 128) ? (rgb + ((size_t)b * 128 + c) * NPIX)
                                     : (ir + ((size_t)b * 128 + (c - 128)) * NPIX);
        T[cc + cg][pl] = f2b(src[pix0 + pl]);
    }
    __syncthreads();
    const int nl = tid >> 2, c0 = (tid & 3) * 8;
    ushort tmp[8];
    #pragma unroll
    for (int j = 0; j < 8; ++j) tmp[j] = T[c0 + j][nl];
    uint4 v;
    v.x = tmp[0] | ((uint)tmp[1] << 16);
    v.y = tmp[2] | ((uint)tmp[3] << 16);
    v.z = tmp[4] | ((uint)tmp[5] << 16);
    v.w = tmp[6] | ((uint)tmp[7] << 16);
    *(uint4*)(&Yb[((size_t)(b * NPIX + pix0 + nl)) * CDIM + cb * 32 + c0]) = v;
}

// ---------------------------------------------------------------------------
// m97-style MFMA NT GEMM body: 128x128 tile, BK=32, unpadded LDS [m][k],
// global_load_lds width=16 staging. MFMA operands SWAPPED (o = A operand) so
// D rows (=regs) are the o-dim -> vectorizable epilogue stores.
// acc[i][j]: i = n-frag, j = o-frag; reg r = o offset, lane&15 = n offset.
// ---------------------------------------------------------------------------
__device__ __forceinline__ void gemm_nt_body(
    const ushort* __restrict__ A, const ushort* __restrict__ W,
    ushort* As, ushort* Bs, int n0, int o0, floatx4 acc[4][4])
{
    const int tid = threadIdx.x;
    const int lane = tid & 63;
    const int wave = tid >> 6;
    const int wr = wave >> 1, wc = wave & 1;
    const int l15 = lane & 15, quad = lane >> 4;

    const int srow = tid >> 2;          // 0..63
    const int sk   = (tid & 3) * 8;     // 0,8,16,24

    for (int k0 = 0; k0 < CDIM; k0 += 32) {
        #pragma unroll
        for (int p = 0; p < 2; ++p) {
            gload_lds16(&A[(size_t)(n0 + p * 64 + srow) * CDIM + k0 + sk],
                        As + wave * 512 + p * 2048);
            gload_lds16(&W[(size_t)(o0 + p * 64 + srow) * CDIM + k0 + sk],
                        Bs + wave * 512 + p * 2048);
        }
        __syncthreads();
        short8 af[4], bfr[4];
        #pragma unroll
        for (int i = 0; i < 4; ++i)
            af[i] = *(const short8*)(&As[(wr * 64 + i * 16 + l15) * 32 + quad * 8]);
        #pragma unroll
        for (int j = 0; j < 4; ++j)
            bfr[j] = *(const short8*)(&Bs[(wc * 64 + j * 16 + l15) * 32 + quad * 8]);
        #pragma unroll
        for (int i = 0; i < 4; ++i)
            #pragma unroll
            for (int j = 0; j < 4; ++j)
                acc[i][j] = __builtin_amdgcn_mfma_f32_16x16x32_bf16(
                    bfr[j], af[i], acc[i][j], 0, 0, 0);   // swapped: rows=o
        __syncthreads();
    }
}

// ---------------------------------------------------------------------------
// QKV GEMM. Output chunk-major qkv2[chunk][n][32], chunk = o>>5
// (chunk 0..7 = Q(dil,head), 8..15 = K, 16..23 = V). 8B packed stores.
// ---------------------------------------------------------------------------
__global__ __launch_bounds__(256) void gemm_qkv_mfma(
    const ushort* __restrict__ Yb, const ushort* __restrict__ Wb,
    ushort* __restrict__ qkv2)
{
    __shared__ __align__(16) ushort As[128 * 32];
    __shared__ __align__(16) ushort Bs[128 * 32];
    const int tid = threadIdx.x;
    const int lane = tid & 63;
    const int wave = tid >> 6;
    const int wr = wave >> 1, wc = wave & 1;
    const int l15 = lane & 15, quad = lane >> 4;
    const int n0 = blockIdx.x * 128;
    const int o0 = blockIdx.y * 128;

    floatx4 acc[4][4] = {};
    gemm_nt_body(Yb, Wb, As, Bs, n0, o0, acc);

    #pragma unroll
    for (int i = 0; i < 4; ++i) {
        const int n = n0 + wr * 64 + i * 16 + l15;
        #pragma unroll
        for (int j = 0; j < 4; ++j) {
            const int o4 = o0 + wc * 64 + j * 16 + quad * 4;   // 4 consecutive o
            uint2 v;
            v.x = f2b(acc[i][j][0]) | ((uint)f2b(acc[i][j][1]) << 16);
            v.y = f2b(acc[i][j][2]) | ((uint)f2b(acc[i][j][3]) << 16);
            *(uint2*)(qkv2 + (size_t)(o4 >> 5) * BN * 32 + (size_t)n * 32 + (o4 & 31)) = v;
        }
    }
}

// ---------------------------------------------------------------------------
// Tiled dilated local attention, two-phase K/V staging through ONE 31 KB LDS
// buffer. One block = (b, dil, head) x 16x16 pixel tile.
// EDGE=false (interior tiles, 9/25): no clamps/masks. V DMA issued before
// softmax math to overlap. OOB (EDGE): score 0 in softmax denom, value 0.
// ---------------------------------------------------------------------------
template<int D, bool EDGE>
__device__ __forceinline__ void attn_tile(
    const ushort* __restrict__ qkv2, ushort* __restrict__ X2,
    ushort* kl, int b, int dh, int y0, int x0)
{
    constexpr int RW = 16 + 2 * D;
    constexpr int RP = RW * RW;
    const int tid = threadIdx.x;
    const int lane = tid & 63;
    const int wave = tid >> 6;          // = channel chunk c (0..3) for staging
    const ushort* Qc = qkv2 + (size_t)dh * BN * 32;
    const ushort* Kc = qkv2 + (size_t)(8 + dh) * BN * 32;
    const ushort* Vc = qkv2 + (size_t)(16 + dh) * BN * 32;

    const int px = tid & 15, py = tid >> 4;
    const int n = b * NPIX + (y0 + py) * WW + (x0 + px);
    float q[32];
    {
        const uint4* qp = (const uint4*)(Qc + (size_t)n * 32);
        uint4 v0 = qp[0], v1 = qp[1], v2 = qp[2], v3 = qp[3];
        unpack8(v0, q); unpack8(v1, q + 8); unpack8(v2, q + 16); unpack8(v3, q + 24);
    }

    // phase 1: stage K region (wave w = channel chunk w; LDS [c][p][16B])
    #pragma unroll 2
    for (int p0 = 0; p0 < RP; p0 += 64) {
        int p = p0 + lane;
        int ry = p / RW, rx = p % RW;
        int gy = y0 - D + ry, gx = x0 - D + rx;
        if (EDGE) { gy = min(max(gy, 0), HH - 1); gx = min(max(gx, 0), WW - 1); }
        if (p < RP)
            gload_lds16(Kc + (size_t)(b * NPIX + gy * WW + gx) * 32 + wave * 8,
                        kl + (size_t)(wave * RP + p0) * 8);
    }
    __syncthreads();

    float sc[9];
    #pragma unroll
    for (int t = 0; t < 9; ++t) {
        const int dy = t / 3 - 1, dx = t % 3 - 1;
        const int p = (py + D + dy * D) * RW + (px + D + dx * D);
        float s = 0.f;
        bool ok = true;
        if (EDGE) {
            const int yy = y0 + py + dy * D, xx = x0 + px + dx * D;
            ok = (yy >= 0 && yy < HH && xx >= 0 && xx < WW);
        }
        if (ok) {
            #pragma unroll
            for (int c = 0; c < 4; ++c) {
                float kv[8];
                unpack8(*(const uint4*)(kl + (size_t)(c * RP + p) * 8), kv);
                #pragma unroll
                for (int j = 0; j < 8; ++j) s += q[c * 8 + j] * kv[j];
            }
        }
        sc[t] = s * SCALE;              // OOB stays exactly 0 (in softmax denom)
    }
    __syncthreads();                    // all waves done reading K

    // phase 2: issue V DMA first, then softmax math (overlap)
    #pragma unroll 2
    for (int p0 = 0; p0 < RP; p0 += 64) {
        int p = p0 + lane;
        int ry = p / RW, rx = p % RW;
        int gy = y0 - D + ry, gx = x0 - D + rx;
        if (EDGE) { gy = min(max(gy, 0), HH - 1); gx = min(max(gx, 0), WW - 1); }
        if (p < RP)
            gload_lds16(Vc + (size_t)(b * NPIX + gy * WW + gx) * 32 + wave * 8,
                        kl + (size_t)(wave * RP + p0) * 8);
    }

    float m = sc[0];
    #pragma unroll
    for (int t = 1; t < 9; ++t) m = fmaxf(m, sc[t]);
    float sum = 0.f;
    #pragma unroll
    for (int t = 0; t < 9; ++t) { sc[t] = __expf(sc[t] - m); sum += sc[t]; }
    const float inv = 1.f / sum;
    __syncthreads();                    // V DMA landed (vmcnt drained at barrier)

    float o[32];
    #pragma unroll
    for (int hd = 0; hd < 32; ++hd) o[hd] = 0.f;
    #pragma unroll
    for (int t = 0; t < 9; ++t) {
        const int dy = t / 3 - 1, dx = t % 3 - 1;
        const int p = (py + D + dy * D) * RW + (px + D + dx * D);
        bool ok = true;
        if (EDGE) {
            const int yy = y0 + py + dy * D, xx = x0 + px + dx * D;
            ok = (yy >= 0 && yy < HH && xx >= 0 && xx < WW);
        }
        if (ok) {
            const float wgt = sc[t] * inv;
            #pragma unroll
            for (int c = 0; c < 4; ++c) {
                float vv[8];
                unpack8(*(const uint4*)(kl + (size_t)(c * RP + p) * 8), vv);
                #pragma unroll
                for (int j = 0; j < 8; ++j) o[c * 8 + j] += wgt * vv[j];
            }
        }
    }
    uint4* xp = (uint4*)(X2 + (size_t)dh * BN * 32 + (size_t)n * 32);
    #pragma unroll
    for (int m4 = 0; m4 < 4; ++m4) {
        uint4 v;
        v.x = f2b(o[8 * m4 + 0]) | ((uint)f2b(o[8 * m4 + 1]) << 16);
        v.y = f2b(o[8 * m4 + 2]) | ((uint)f2b(o[8 * m4 + 3]) << 16);
        v.z = f2b(o[8 * m4 + 4]) | ((uint)f2b(o[8 * m4 + 5]) << 16);
        v.w = f2b(o[8 * m4 + 6]) | ((uint)f2b(o[8 * m4 + 7]) << 16);
        xp[m4] = v;
    }
}

__global__ __launch_bounds__(256) void attn2_k(
    const ushort* __restrict__ qkv2, ushort* __restrict__ X2)
{
    __shared__ __align__(16) ushort kl[4 * 484 * 8];   // 31 KB (worst case d=3)
    const int tile = blockIdx.x;                       // 0..24
    const int y0 = (tile / 5) * 16, x0 = (tile % 5) * 16;
    const int dh = blockIdx.y;                         // dil*4 + head
    const int b = blockIdx.z;
    const bool inter = (y0 >= 16 && y0 <= 48 && x0 >= 16 && x0 <= 48);
    if (dh < 4) {
        if (inter) attn_tile<2, false>(qkv2, X2, kl, b, dh, y0, x0);
        else       attn_tile<2, true >(qkv2, X2, kl, b, dh, y0, x0);
    } else {
        if (inter) attn_tile<3, false>(qkv2, X2, kl, b, dh, y0, x0);
        else       attn_tile<3, true >(qkv2, X2, kl, b, dh, y0, x0);
    }
}

// ---------------------------------------------------------------------------
// MFMA NT GEMM + epilogue: out[n][co] = X·Wp^T + bias + Y residual (fp32 out).
// A staged chunk-wise from X2 (k0-chunk == dh chunk). float4 stores,
// float4 bias + ushort4 residual loads (regs = 4 consecutive co).
// ---------------------------------------------------------------------------
__global__ __launch_bounds__(256) void proj_mfma(
    const ushort* __restrict__ X2, const ushort* __restrict__ Wpb,
    const float* __restrict__ bp, const ushort* __restrict__ Yb,
    float* __restrict__ out)
{
    __shared__ __align__(16) ushort As[128 * 32];
    __shared__ __align__(16) ushort Bs[128 * 32];
    const int tid = threadIdx.x;
    const int lane = tid & 63;
    const int wave = tid >> 6;
    const int wr = wave >> 1, wc = wave & 1;
    const int l15 = lane & 15, quad = lane >> 4;
    const int n0 = blockIdx.x * 128;
    const int o0 = blockIdx.y * 128;

    const int srow = tid >> 2;
    const int sk   = (tid & 3) * 8;

    floatx4 acc[4][4] = {};

    for (int k0 = 0; k0 < CDIM; k0 += 32) {
        const ushort* Achunk = X2 + (size_t)(k0 >> 5) * BN * 32;
        #pragma unroll
        for (int p = 0; p < 2; ++p) {
            gload_lds16(&Achunk[(size_t)(n0 + p * 64 + srow) * 32 + sk],
                        As + wave * 512 + p * 2048);
            gload_lds16(&Wpb[(size_t)(o0 + p * 64 + srow) * CDIM + k0 + sk],
                        Bs + wave * 512 + p * 2048);
        }
        __syncthreads();
        short8 af[4], bfr[4];
        #pragma unroll
        for (int i = 0; i < 4; ++i)
            af[i] = *(const short8*)(&As[(wr * 64 + i * 16 + l15) * 32 + quad * 8]);
        #pragma unroll
        for (int j = 0; j < 4; ++j)
            bfr[j] = *(const short8*)(&Bs[(wc * 64 + j * 16 + l15) * 32 + quad * 8]);
        #pragma unroll
        for (int i = 0; i < 4; ++i)
            #pragma unroll
            for (int j = 0; j < 4; ++j)
                acc[i][j] = __builtin_amdgcn_mfma_f32_16x16x32_bf16(
                    bfr[j], af[i], acc[i][j], 0, 0, 0);   // swapped: rows=o
        __syncthreads();
    }

    #pragma unroll
    for (int i = 0; i < 4; ++i) {
        const int n = n0 + wr * 64 + i * 16 + l15;
        #pragma unroll
        for (int j = 0; j < 4; ++j) {
            const int o4 = o0 + wc * 64 + j * 16 + quad * 4;   // 4 consecutive co
            const float4 bias = *(const float4*)(bp + o4);
            const ushort4 res = *(const ushort4*)(Yb + (size_t)n * CDIM + o4);
            float4 v;
            v.x = acc[i][j][0] + bias.x + b2f(res.x);
            v.y = acc[i][j][1] + bias.y + b2f(res.y);
            v.z = acc[i][j][2] + bias.z + b2f(res.z);
            v.w = acc[i][j][3] + bias.w + b2f(res.w);
            *(float4*)(out + (size_t)n * CDIM + o4) = v;
        }
    }
}

extern "C" void kernel_launch(void* const* d_in, const int* in_sizes, int n_in,
                              void* d_out, int out_size, void* d_ws, size_t ws_size,
                              hipStream_t stream) {
    const float* rgb    = (const float*)d_in[0];
    const float* ir     = (const float*)d_in[1];
    const float* w_qkv  = (const float*)d_in[2];
    const float* w_proj = (const float*)d_in[3];
    const float* b_proj = (const float*)d_in[4];
    float* out = (float*)d_out;

    ushort* qkv2 = (ushort*)d_ws;                    // 24 chunks * 25600*32 = 39.3 MB
    ushort* Yb   = qkv2 + (size_t)24 * BN * 32;      // 25600*256 = 13.1 MB
    ushort* X2   = Yb + (size_t)BN * CDIM;           // 8 chunks * 25600*32 = 13.1 MB
    ushort* Wqb  = X2 + (size_t)8 * BN * 32;         // 768*256
    ushort* Wpb  = Wqb + (size_t)QKVC * CDIM;        // 256*256

    cast_all_k<<<dim3(132, 8, NB), 256, 0, stream>>>(rgb, ir, w_qkv, w_proj,
                                                     Yb, Wqb, Wpb);
    gemm_qkv_mfma<<<dim3(BN / 128, QKVC / 128), 256, 0, stream>>>(Yb, Wqb, qkv2);
    attn2_k<<<dim3(25, 8, NB), 256, 0, stream>>>(qkv2, X2);
    proj_mfma<<<dim3(BN / 128, CDIM / 128), 256, 0, stream>>>(X2, Wpb, b_proj, Yb, out);
}

// Round 7
// 135.574 us; speedup vs baseline: 2.4355x; 1.0032x over previous
//
#include <hip/hip_runtime.h>

#define HH 80
#define WW 80
#define NPIX 6400          // 80*80
#define NB 4
#define BN 25600           // NB * NPIX
#define CDIM 256
#define QKVC 768
#define SCALE 0.17677669529663689f   // 32^-0.5

typedef __attribute__((ext_vector_type(8))) short short8;
typedef __attribute__((ext_vector_type(4))) float floatx4;

__device__ __forceinline__ float b2f(ushort u) {
    return __uint_as_float(((uint)u) << 16);
}
__device__ __forceinline__ ushort f2b(float f) {
    uint u = __float_as_uint(f);
    return (ushort)((u + 0x7fffu + ((u >> 16) & 1u)) >> 16);   // RNE
}
__device__ __forceinline__ void unpack8(uint4 v, float* f) {
    f[0] = __uint_as_float(v.x << 16); f[1] = __uint_as_float(v.x & 0xffff0000u);
    f[2] = __uint_as_float(v.y << 16); f[3] = __uint_as_float(v.y & 0xffff0000u);
    f[4] = __uint_as_float(v.z << 16); f[5] = __uint_as_float(v.z & 0xffff0000u);
    f[6] = __uint_as_float(v.w << 16); f[7] = __uint_as_float(v.w & 0xffff0000u);
}
__device__ __forceinline__ void gload_lds16(const void* gptr, void* lptr) {
    __builtin_amdgcn_global_load_lds(
        (const __attribute__((address_space(1))) unsigned int*)gptr,
        (__attribute__((address_space(3))) unsigned int*)lptr,
        16, 0, 0);
}

// ---------------------------------------------------------------------------
// Fused cast kernel.
//  blocks x <  100: Yb[n][c] = bf16(concat(rgb, ir)) via LDS transpose tile
//  blocks x >= 100: cast w_qkv / w_proj to bf16 (flat)
// ---------------------------------------------------------------------------
__global__ __launch_bounds__(256) void cast_all_k(
    const float* __restrict__ rgb, const float* __restrict__ ir,
    const float* __restrict__ wq, const float* __restrict__ wp,
    ushort* __restrict__ Yb, ushort* __restrict__ wqb, ushort* __restrict__ wpb)
{
    const int tid = threadIdx.x;
    if (blockIdx.x >= 100) {
        int i = (((blockIdx.x - 100) * 8 + blockIdx.y) * 4 + blockIdx.z) * 256 + tid;
        if (i < QKVC * CDIM) wqb[i] = f2b(wq[i]);
        else                 wpb[i - QKVC * CDIM] = f2b(wp[i - QKVC * CDIM]);
        return;
    }
    __shared__ ushort T[32][72];
    const int pix0 = blockIdx.x * 64;
    const int cb = blockIdx.y;
    const int b = blockIdx.z;

    const int pl = tid & 63, cg = tid >> 6;
    #pragma unroll
    for (int cc = 0; cc < 32; cc += 4) {
        int c = cb * 32 + cc + cg;
        const float* src = (c < 128) ? (rgb + ((size_t)b * 128 + c) * NPIX)
                                     : (ir + ((size_t)b * 128 + (c - 128)) * NPIX);
        T[cc + cg][pl] = f2b(src[pix0 + pl]);
    }
    __syncthreads();
    const int nl = tid >> 2, c0 = (tid & 3) * 8;
    ushort tmp[8];
    #pragma unroll
    for (int j = 0; j < 8; ++j) tmp[j] = T[c0 + j][nl];
    uint4 v;
    v.x = tmp[0] | ((uint)tmp[1] << 16);
    v.y = tmp[2] | ((uint)tmp[3] << 16);
    v.z = tmp[4] | ((uint)tmp[5] << 16);
    v.w = tmp[6] | ((uint)tmp[7] << 16);
    *(uint4*)(&Yb[((size_t)(b * NPIX + pix0 + nl)) * CDIM + cb * 32 + c0]) = v;
}

// ---------------------------------------------------------------------------
// BK=64 MFMA NT GEMM body. 128x128 tile, 4 K-iters (half the barriers of
// BK=32). Unpadded LDS [m][64] with parity-XOR swizzle: odd rows store their
// two 32-elem k-halves swapped (scol = k ^ ((row&1)<<5)), applied on the
// GLOBAL address so the global_load_lds DMA stays flat+contiguous (m104) and
// each 8-lane group still reads one 128 B line. Frag reads then spread across
// all 32 banks (even rows +s*16 dwords, odd rows +(1-s)*16) -> conflict-free.
// MFMA operands swapped (o = A operand): acc reg r = o offset, lane&15 = n.
// ---------------------------------------------------------------------------
__device__ __forceinline__ void gemm_nt_body64(
    const ushort* __restrict__ A, const ushort* __restrict__ W,
    ushort* As, ushort* Bs, int n0, int o0, floatx4 acc[4][4])
{
    const int tid = threadIdx.x;
    const int lane = tid & 63;
    const int wave = tid >> 6;
    const int wr = wave >> 1, wc = wave & 1;
    const int l15 = lane & 15, quad = lane >> 4;

    const int srow8 = tid >> 3;                        // row within 32-row round
    const int scol  = ((tid & 7) * 8) ^ ((srow8 & 1) << 5);
    const int par   = l15 & 1;                         // frag-row parity

    for (int k0 = 0; k0 < CDIM; k0 += 64) {
        #pragma unroll
        for (int r = 0; r < 4; ++r) {
            const int row = r * 32 + srow8;
            gload_lds16(&A[(size_t)(n0 + row) * CDIM + k0 + scol],
                        As + r * 2048 + wave * 512);
            gload_lds16(&W[(size_t)(o0 + row) * CDIM + k0 + scol],
                        Bs + r * 2048 + wave * 512);
        }
        __syncthreads();
        #pragma unroll
        for (int s = 0; s < 2; ++s) {
            const int fc = ((s ^ par) << 5) + quad * 8;
            short8 af[4], bfr[4];
            #pragma unroll
            for (int i = 0; i < 4; ++i)
                af[i] = *(const short8*)(&As[(wr * 64 + i * 16 + l15) * 64 + fc]);
            #pragma unroll
            for (int j = 0; j < 4; ++j)
                bfr[j] = *(const short8*)(&Bs[(wc * 64 + j * 16 + l15) * 64 + fc]);
            #pragma unroll
            for (int i = 0; i < 4; ++i)
                #pragma unroll
                for (int j = 0; j < 4; ++j)
                    acc[i][j] = __builtin_amdgcn_mfma_f32_16x16x32_bf16(
                        bfr[j], af[i], acc[i][j], 0, 0, 0);   // swapped: rows=o
        }
        __syncthreads();
    }
}

// ---------------------------------------------------------------------------
// QKV GEMM. Output chunk-major qkv2[chunk][n][32], chunk = o>>5
// (chunk 0..7 = Q(dil,head), 8..15 = K, 16..23 = V). 8B packed stores.
// ---------------------------------------------------------------------------
__global__ __launch_bounds__(256) void gemm_qkv_mfma(
    const ushort* __restrict__ Yb, const ushort* __restrict__ Wb,
    ushort* __restrict__ qkv2)
{
    __shared__ __align__(16) ushort As[128 * 64];
    __shared__ __align__(16) ushort Bs[128 * 64];
    const int tid = threadIdx.x;
    const int lane = tid & 63;
    const int wave = tid >> 6;
    const int wr = wave >> 1, wc = wave & 1;
    const int l15 = lane & 15, quad = lane >> 4;
    const int n0 = blockIdx.x * 128;
    const int o0 = blockIdx.y * 128;

    floatx4 acc[4][4] = {};
    gemm_nt_body64(Yb, Wb, As, Bs, n0, o0, acc);

    #pragma unroll
    for (int i = 0; i < 4; ++i) {
        const int n = n0 + wr * 64 + i * 16 + l15;
        #pragma unroll
        for (int j = 0; j < 4; ++j) {
            const int o4 = o0 + wc * 64 + j * 16 + quad * 4;   // 4 consecutive o
            uint2 v;
            v.x = f2b(acc[i][j][0]) | ((uint)f2b(acc[i][j][1]) << 16);
            v.y = f2b(acc[i][j][2]) | ((uint)f2b(acc[i][j][3]) << 16);
            *(uint2*)(qkv2 + (size_t)(o4 >> 5) * BN * 32 + (size_t)n * 32 + (o4 & 31)) = v;
        }
    }
}

// ---------------------------------------------------------------------------
// Tiled dilated local attention, two-phase K/V staging through ONE 31 KB LDS
// buffer. One block = (b, dil, head) x 16x16 pixel tile.
// EDGE=false (interior tiles, 9/25): no clamps/masks. V DMA issued before
// softmax math to overlap. OOB (EDGE): score 0 in softmax denom, value 0.
// ---------------------------------------------------------------------------
template<int D, bool EDGE>
__device__ __forceinline__ void attn_tile(
    const ushort* __restrict__ qkv2, ushort* __restrict__ X2,
    ushort* kl, int b, int dh, int y0, int x0)
{
    constexpr int RW = 16 + 2 * D;
    constexpr int RP = RW * RW;
    const int tid = threadIdx.x;
    const int lane = tid & 63;
    const int wave = tid >> 6;          // = channel chunk c (0..3) for staging
    const ushort* Qc = qkv2 + (size_t)dh * BN * 32;
    const ushort* Kc = qkv2 + (size_t)(8 + dh) * BN * 32;
    const ushort* Vc = qkv2 + (size_t)(16 + dh) * BN * 32;

    const int px = tid & 15, py = tid >> 4;
    const int n = b * NPIX + (y0 + py) * WW + (x0 + px);
    float q[32];
    {
        const uint4* qp = (const uint4*)(Qc + (size_t)n * 32);
        uint4 v0 = qp[0], v1 = qp[1], v2 = qp[2], v3 = qp[3];
        unpack8(v0, q); unpack8(v1, q + 8); unpack8(v2, q + 16); unpack8(v3, q + 24);
    }

    // phase 1: stage K region (wave w = channel chunk w; LDS [c][p][16B])
    #pragma unroll 2
    for (int p0 = 0; p0 < RP; p0 += 64) {
        int p = p0 + lane;
        int ry = p / RW, rx = p % RW;
        int gy = y0 - D + ry, gx = x0 - D + rx;
        if (EDGE) { gy = min(max(gy, 0), HH - 1); gx = min(max(gx, 0), WW - 1); }
        if (p < RP)
            gload_lds16(Kc + (size_t)(b * NPIX + gy * WW + gx) * 32 + wave * 8,
                        kl + (size_t)(wave * RP + p0) * 8);
    }
    __syncthreads();

    float sc[9];
    #pragma unroll
    for (int t = 0; t < 9; ++t) {
        const int dy = t / 3 - 1, dx = t % 3 - 1;
        const int p = (py + D + dy * D) * RW + (px + D + dx * D);
        float s = 0.f;
        bool ok = true;
        if (EDGE) {
            const int yy = y0 + py + dy * D, xx = x0 + px + dx * D;
            ok = (yy >= 0 && yy < HH && xx >= 0 && xx < WW);
        }
        if (ok) {
            #pragma unroll
            for (int c = 0; c < 4; ++c) {
                float kv[8];
                unpack8(*(const uint4*)(kl + (size_t)(c * RP + p) * 8), kv);
                #pragma unroll
                for (int j = 0; j < 8; ++j) s += q[c * 8 + j] * kv[j];
            }
        }
        sc[t] = s * SCALE;              // OOB stays exactly 0 (in softmax denom)
    }
    __syncthreads();                    // all waves done reading K

    // phase 2: issue V DMA first, then softmax math (overlap)
    #pragma unroll 2
    for (int p0 = 0; p0 < RP; p0 += 64) {
        int p = p0 + lane;
        int ry = p / RW, rx = p % RW;
        int gy = y0 - D + ry, gx = x0 - D + rx;
        if (EDGE) { gy = min(max(gy, 0), HH - 1); gx = min(max(gx, 0), WW - 1); }
        if (p < RP)
            gload_lds16(Vc + (size_t)(b * NPIX + gy * WW + gx) * 32 + wave * 8,
                        kl + (size_t)(wave * RP + p0) * 8);
    }

    float m = sc[0];
    #pragma unroll
    for (int t = 1; t < 9; ++t) m = fmaxf(m, sc[t]);
    float sum = 0.f;
    #pragma unroll
    for (int t = 0; t < 9; ++t) { sc[t] = __expf(sc[t] - m); sum += sc[t]; }
    const float inv = 1.f / sum;
    __syncthreads();                    // V DMA landed (vmcnt drained at barrier)

    float o[32];
    #pragma unroll
    for (int hd = 0; hd < 32; ++hd) o[hd] = 0.f;
    #pragma unroll
    for (int t = 0; t < 9; ++t) {
        const int dy = t / 3 - 1, dx = t % 3 - 1;
        const int p = (py + D + dy * D) * RW + (px + D + dx * D);
        bool ok = true;
        if (EDGE) {
            const int yy = y0 + py + dy * D, xx = x0 + px + dx * D;
            ok = (yy >= 0 && yy < HH && xx >= 0 && xx < WW);
        }
        if (ok) {
            const float wgt = sc[t] * inv;
            #pragma unroll
            for (int c = 0; c < 4; ++c) {
                float vv[8];
                unpack8(*(const uint4*)(kl + (size_t)(c * RP + p) * 8), vv);
                #pragma unroll
                for (int j = 0; j < 8; ++j) o[c * 8 + j] += wgt * vv[j];
            }
        }
    }
    uint4* xp = (uint4*)(X2 + (size_t)dh * BN * 32 + (size_t)n * 32);
    #pragma unroll
    for (int m4 = 0; m4 < 4; ++m4) {
        uint4 v;
        v.x = f2b(o[8 * m4 + 0]) | ((uint)f2b(o[8 * m4 + 1]) << 16);
        v.y = f2b(o[8 * m4 + 2]) | ((uint)f2b(o[8 * m4 + 3]) << 16);
        v.z = f2b(o[8 * m4 + 4]) | ((uint)f2b(o[8 * m4 + 5]) << 16);
        v.w = f2b(o[8 * m4 + 6]) | ((uint)f2b(o[8 * m4 + 7]) << 16);
        xp[m4] = v;
    }
}

__global__ __launch_bounds__(256) void attn2_k(
    const ushort* __restrict__ qkv2, ushort* __restrict__ X2)
{
    __shared__ __align__(16) ushort kl[4 * 484 * 8];   // 31 KB (worst case d=3)
    const int tile = blockIdx.x;                       // 0..24
    const int y0 = (tile / 5) * 16, x0 = (tile % 5) * 16;
    const int dh = blockIdx.y;                         // dil*4 + head
    const int b = blockIdx.z;
    const bool inter = (y0 >= 16 && y0 <= 48 && x0 >= 16 && x0 <= 48);
    if (dh < 4) {
        if (inter) attn_tile<2, false>(qkv2, X2, kl, b, dh, y0, x0);
        else       attn_tile<2, true >(qkv2, X2, kl, b, dh, y0, x0);
    } else {
        if (inter) attn_tile<3, false>(qkv2, X2, kl, b, dh, y0, x0);
        else       attn_tile<3, true >(qkv2, X2, kl, b, dh, y0, x0);
    }
}

// ---------------------------------------------------------------------------
// BK=64 MFMA NT GEMM + epilogue: out[n][co] = X·Wp^T + bias + Y residual.
// A staged from chunk-major X2: the XOR swizzle's bit-5 flip selects between
// the two 32-wide chunks spanned by BK=64 (chunk_sel), offset = (tid&3)*8.
// ---------------------------------------------------------------------------
__global__ __launch_bounds__(256) void proj_mfma(
    const ushort* __restrict__ X2, const ushort* __restrict__ Wpb,
    const float* __restrict__ bp, const ushort* __restrict__ Yb,
    float* __restrict__ out)
{
    __shared__ __align__(16) ushort As[128 * 64];
    __shared__ __align__(16) ushort Bs[128 * 64];
    const int tid = threadIdx.x;
    const int lane = tid & 63;
    const int wave = tid >> 6;
    const int wr = wave >> 1, wc = wave & 1;
    const int l15 = lane & 15, quad = lane >> 4;
    const int n0 = blockIdx.x * 128;
    const int o0 = blockIdx.y * 128;

    const int srow8 = tid >> 3;
    const int scol  = ((tid & 7) * 8) ^ ((srow8 & 1) << 5);
    const int chunk_sel = ((tid >> 2) & 1) ^ (srow8 & 1);
    const int coff  = (tid & 3) * 8;
    const int par   = l15 & 1;

    floatx4 acc[4][4] = {};

    for (int k0 = 0; k0 < CDIM; k0 += 64) {
        const int cbase = k0 >> 5;
        const ushort* Achunk = X2 + (size_t)(cbase + chunk_sel) * BN * 32;
        #pragma unroll
        for (int r = 0; r < 4; ++r) {
            const int row = r * 32 + srow8;
            gload_lds16(&Achunk[(size_t)(n0 + row) * 32 + coff],
                        As + r * 2048 + wave * 512);
            gload_lds16(&Wpb[(size_t)(o0 + row) * CDIM + k0 + scol],
                        Bs + r * 2048 + wave * 512);
        }
        __syncthreads();
        #pragma unroll
        for (int s = 0; s < 2; ++s) {
            const int fc = ((s ^ par) << 5) + quad * 8;
            short8 af[4], bfr[4];
            #pragma unroll
            for (int i = 0; i < 4; ++i)
                af[i] = *(const short8*)(&As[(wr * 64 + i * 16 + l15) * 64 + fc]);
            #pragma unroll
            for (int j = 0; j < 4; ++j)
                bfr[j] = *(const short8*)(&Bs[(wc * 64 + j * 16 + l15) * 64 + fc]);
            #pragma unroll
            for (int i = 0; i < 4; ++i)
                #pragma unroll
                for (int j = 0; j < 4; ++j)
                    acc[i][j] = __builtin_amdgcn_mfma_f32_16x16x32_bf16(
                        bfr[j], af[i], acc[i][j], 0, 0, 0);   // swapped: rows=o
        }
        __syncthreads();
    }

    #pragma unroll
    for (int i = 0; i < 4; ++i) {
        const int n = n0 + wr * 64 + i * 16 + l15;
        #pragma unroll
        for (int j = 0; j < 4; ++j) {
            const int o4 = o0 + wc * 64 + j * 16 + quad * 4;   // 4 consecutive co
            const float4 bias = *(const float4*)(bp + o4);
            const ushort4 res = *(const ushort4*)(Yb + (size_t)n * CDIM + o4);
            float4 v;
            v.x = acc[i][j][0] + bias.x + b2f(res.x);
            v.y = acc[i][j][1] + bias.y + b2f(res.y);
            v.z = acc[i][j][2] + bias.z + b2f(res.z);
            v.w = acc[i][j][3] + bias.w + b2f(res.w);
            *(float4*)(out + (size_t)n * CDIM + o4) = v;
        }
    }
}

extern "C" void kernel_launch(void* const* d_in, const int* in_sizes, int n_in,
                              void* d_out, int out_size, void* d_ws, size_t ws_size,
                              hipStream_t stream) {
    const float* rgb    = (const float*)d_in[0];
    const float* ir     = (const float*)d_in[1];
    const float* w_qkv  = (const float*)d_in[2];
    const float* w_proj = (const float*)d_in[3];
    const float* b_proj = (const float*)d_in[4];
    float* out = (float*)d_out;

    ushort* qkv2 = (ushort*)d_ws;                    // 24 chunks * 25600*32 = 39.3 MB
    ushort* Yb   = qkv2 + (size_t)24 * BN * 32;      // 25600*256 = 13.1 MB
    ushort* X2   = Yb + (size_t)BN * CDIM;           // 8 chunks * 25600*32 = 13.1 MB
    ushort* Wqb  = X2 + (size_t)8 * BN * 32;         // 768*256
    ushort* Wpb  = Wqb + (size_t)QKVC * CDIM;        // 256*256

    cast_all_k<<<dim3(132, 8, NB), 256, 0, stream>>>(rgb, ir, w_qkv, w_proj,
                                                     Yb, Wqb, Wpb);
    gemm_qkv_mfma<<<dim3(BN / 128, QKVC / 128), 256, 0, stream>>>(Yb, Wqb, qkv2);
    attn2_k<<<dim3(25, 8, NB), 256, 0, stream>>>(qkv2, X2);
    proj_mfma<<<dim3(BN / 128, CDIM / 128), 256, 0, stream>>>(X2, Wpb, b_proj, Yb, out);
}